// Round 15
// baseline (108.450 us; speedup 1.0000x reference)
//
#include <hip/hip_runtime.h>
#include <cstdint>
#include <cstddef>

#define S_TOT 2048
#define S0_   1023
#define S1_   1025
#define D_    256
#define D2_   512
#define DZ_   128
#define NB_   8
#define NT_   17            // 17 * 64 padded keys = 1088
#define KT16_ 68            // 17*4 16-key groups
#define SCALE_INV (1.0f/16.0f)
#define XPAD  264           // 256 + 8 bf16 pad
#define UPAD  520           // 512 + 8 bf16 pad
#define NTILES (NB_*S0_*NT_)        // 139128 mask tiles
#define MP_BLOCKS ((NTILES + 15)/16) // 16 tiles/block (4 per wave)

typedef __attribute__((ext_vector_type(8))) short short8v;
typedef __attribute__((ext_vector_type(4))) short short4v;
typedef __attribute__((ext_vector_type(4))) float f32x4;
typedef unsigned long long u64;

__device__ __forceinline__ short f2bf(float f){
  unsigned u = __float_as_uint(f);
  unsigned r = (u + 0x7FFFu + ((u >> 16) & 1u)) >> 16;
  return (short)r;
}
__device__ __forceinline__ float bf2f(short s){
  return __uint_as_float(((unsigned)(unsigned short)s) << 16);
}
__device__ __forceinline__ float silu_f(float x){ return x / (1.f + __expf(-x)); }

// A/B fragment load from a row-major row (verified layout, round 1):
// elems 0..3: k = kt*32 + khi + j ; elems 4..7: +16
__device__ __forceinline__ short8v load_afrag(const short* arow, int kt, int khi){
  short4v lo = *reinterpret_cast<const short4v*>(arow + kt*32 + khi);
  short4v hi = *reinterpret_cast<const short4v*>(arow + kt*32 + khi + 16);
  short8v r = {lo[0],lo[1],lo[2],lo[3],hi[0],hi[1],hi[2],hi[3]};
  return r;
}

// ------- k_prep: weight packs ONLY (maskpack moved into k_gemmZV) ----------
__global__ __launch_bounds__(256) void k_prep(
    const float* __restrict__ W_init, const float* __restrict__ W_U,
    const float* __restrict__ W_V,    const float* __restrict__ W_Z,
    const float* __restrict__ W_out,  const float* __restrict__ W_gate,
    short* __restrict__ WpI, short* __restrict__ WpU, short* __restrict__ WpV,
    short* __restrict__ WpZ, short* __restrict__ WpO, short* __restrict__ WpG)
{
  const int blk = blockIdx.x;
  const float* W; short* dst; int K, N, base;
  if      (blk <  32){ W=W_init; dst=WpI; K=256; N=256; base=0;   }
  else if (blk <  96){ W=W_U;    dst=WpU; K=256; N=512; base=32;  }
  else if (blk < 160){ W=W_V;    dst=WpV; K=256; N=512; base=96;  }
  else if (blk < 176){ W=W_Z;    dst=WpZ; K=256; N=128; base=160; }
  else if (blk < 240){ W=W_out;  dst=WpO; K=512; N=256; base=176; }
  else               { W=W_gate; dst=WpG; K=512; N=256; base=240; }
  const int wv = threadIdx.x >> 6, lane = threadIdx.x & 63;
  const int KT = K >> 5;
  const int tile = (blk - base)*4 + wv;
  const int nt = tile / KT, kt = tile - nt*KT;
  const int n = nt*16 + (lane & 15);
  const int kbase = kt*32 + ((lane>>4)<<2);
  short8v v;
  #pragma unroll
  for (int j=0;j<8;++j){
    int k = kbase + (j&3) + ((j>>2)<<4);
    v[j] = f2bf(W[(size_t)k*N + n]);
  }
  *reinterpret_cast<short8v*>(dst + ((size_t)tile*64 + lane)*8) = v;
}

// ---------------- kernel 1a: x = LN(seq@W_init + b) -> bf16; tail rows->out -
__global__ __launch_bounds__(256) void k_x(
    const float* __restrict__ seq, const short* __restrict__ Wp,
    const float* __restrict__ b_init,
    const float* __restrict__ ln_g, const float* __restrict__ ln_b,
    short* __restrict__ xb, float* __restrict__ out)
{
  __shared__ short s_a[64*XPAD];
  const int tid = threadIdx.x, lane = tid & 63, wv = tid >> 6;
  const int R0 = blockIdx.x * 64;
  const int colb = lane & 15, khi = (lane>>4)<<2;

  for (int c = tid; c < 64*64; c += 256){
    int row = c >> 6, c4 = (c & 63) << 2;
    int g = R0 + row;
    float4 f = *reinterpret_cast<const float4*>(seq + (size_t)g*D_ + c4);
    short4v h = { f2bf(f.x), f2bf(f.y), f2bf(f.z), f2bf(f.w) };
    *reinterpret_cast<short4v*>(&s_a[row*XPAD + c4]) = h;
    if ((g & 2047) >= S0_)           // passthrough tail rows
      *reinterpret_cast<float4*>(out + (size_t)g*D_ + c4) = f;
  }
  __syncthreads();

  f32x4 acc[16];
  #pragma unroll
  for (int nt=0;nt<16;++nt) acc[nt] = (f32x4){0.f,0.f,0.f,0.f};

  const short* arow = &s_a[(wv*16 + colb)*XPAD];
  #pragma unroll
  for (int kt=0; kt<8; ++kt){
    short8v a = load_afrag(arow, kt, khi);
    #pragma unroll
    for (int nt=0; nt<16; ++nt){
      short8v b = *reinterpret_cast<const short8v*>(Wp + ((size_t)(nt*8 + kt)*64 + lane)*8);
      acc[nt] = __builtin_amdgcn_mfma_f32_16x16x32_bf16(a, b, acc[nt], 0, 0, 0);
    }
  }

  float sum[4] = {0.f,0.f,0.f,0.f};
  #pragma unroll
  for (int nt=0; nt<16; ++nt){
    float bv = b_init[nt*16 + colb];
    #pragma unroll
    for (int r=0;r<4;++r){ acc[nt][r] += bv; sum[r] += acc[nt][r]; }
  }
  #pragma unroll
  for (int r=0;r<4;++r){
    #pragma unroll
    for (int m=1;m<16;m<<=1) sum[r] += __shfl_xor(sum[r], m, 64);
    sum[r] *= (1.f/256.f);
  }
  float var[4] = {0.f,0.f,0.f,0.f};
  #pragma unroll
  for (int nt=0; nt<16; ++nt)
    #pragma unroll
    for (int r=0;r<4;++r){ float d = acc[nt][r]-sum[r]; var[r] += d*d; }
  #pragma unroll
  for (int r=0;r<4;++r){
    #pragma unroll
    for (int m=1;m<16;m<<=1) var[r] += __shfl_xor(var[r], m, 64);
    var[r] = rsqrtf(var[r]*(1.f/256.f) + 1e-5f);
  }
  #pragma unroll
  for (int nt=0; nt<16; ++nt){
    int col = nt*16 + colb;
    float g = ln_g[col], bb = ln_b[col];
    #pragma unroll
    for (int r=0;r<4;++r){
      float xn = (acc[nt][r]-sum[r])*var[r]*g + bb;
      s_a[(wv*16 + ((lane>>4)<<2) + r)*XPAD + col] = f2bf(xn);
    }
  }
  __syncthreads();
  for (int c = tid; c < 64*32; c += 256){
    int row = c >> 5, c8 = (c & 31) << 3;
    *reinterpret_cast<short8v*>(xb + (size_t)(R0+row)*D_ + c8) =
        *reinterpret_cast<const short8v*>(&s_a[row*XPAD + c8]);
  }
}

// ---- k_gemmZV: Z-gemm [0,512) + V-gemm [512,1600) + maskpack [1600,...) ----
__global__ __launch_bounds__(256) void k_gemmZV(
    const short* __restrict__ xb,
    const short* __restrict__ WpZ, const float* __restrict__ b_Z,
    short* __restrict__ Zb,
    const short* __restrict__ WpV, const float* __restrict__ b_V,
    short* __restrict__ VtF,
    const unsigned char* __restrict__ amask, u64* __restrict__ maskb)
{
  __shared__ short s_a[64*XPAD];
  __shared__ short s_t[64][72];
  const int blk = blockIdx.x;
  const int tid = threadIdx.x, lane = tid & 63, wv = tid >> 6;
  const int wy = wv >> 1, wx = wv & 1;
  const int colb = lane & 15, khi = (lane>>4)<<2;

  if (blk < 512){
    const int R0 = (blk >> 1) * 64;
    const int C0 = (blk & 1) * 64;

    for (int c = tid; c < 64*32; c += 256){
      int r = c >> 5, c8 = (c & 31) << 3;
      size_t xrow = (size_t)(R0 + r);
      *reinterpret_cast<short8v*>(&s_a[r*XPAD + c8]) =
          *reinterpret_cast<const short8v*>(xb + xrow*D_ + c8);
    }
    __syncthreads();

    f32x4 acc[2][2];
    #pragma unroll
    for(int i=0;i<2;++i)
      #pragma unroll
      for(int j=0;j<2;++j) acc[i][j] = (f32x4){0.f,0.f,0.f,0.f};

    const short* ar0 = &s_a[(wy*32 + colb)*XPAD];
    const short* ar1 = ar0 + 16*XPAD;
    const int ntg = (C0 >> 4) + wx*2;
    #pragma unroll
    for (int kt=0; kt<8; ++kt){
      short8v a0 = load_afrag(ar0, kt, khi);
      short8v a1 = load_afrag(ar1, kt, khi);
      short8v b0 = *reinterpret_cast<const short8v*>(WpZ + ((size_t)((ntg+0)*8 + kt)*64 + lane)*8);
      short8v b1 = *reinterpret_cast<const short8v*>(WpZ + ((size_t)((ntg+1)*8 + kt)*64 + lane)*8);
      acc[0][0] = __builtin_amdgcn_mfma_f32_16x16x32_bf16(a0, b0, acc[0][0], 0,0,0);
      acc[0][1] = __builtin_amdgcn_mfma_f32_16x16x32_bf16(a0, b1, acc[0][1], 0,0,0);
      acc[1][0] = __builtin_amdgcn_mfma_f32_16x16x32_bf16(a1, b0, acc[1][0], 0,0,0);
      acc[1][1] = __builtin_amdgcn_mfma_f32_16x16x32_bf16(a1, b1, acc[1][1], 0,0,0);
    }
    #pragma unroll
    for (int sj=0; sj<2; ++sj){
      int col = C0 + wx*32 + sj*16 + colb;
      float bv = b_Z[col];
      #pragma unroll
      for (int si=0; si<2; ++si){
        #pragma unroll
        for (int r=0;r<4;++r){
          int orow = R0 + wy*32 + si*16 + ((lane>>4)<<2) + r;
          Zb[(size_t)orow*DZ_ + col] = f2bf(silu_f(acc[si][sj][r] + bv));
        }
      }
    }
  } else if (blk < 1600){
    const int idx = blk - 512;
    const int t   = idx % 17;
    const int rest= idx / 17;
    const int C0  = (rest & 7) * 64;
    const int b   = rest >> 3;
    const int R0  = t * 64;

    for (int c = tid; c < 64*32; c += 256){
      int r = c >> 5, c8 = (c & 31) << 3;
      int k = R0 + r; if (k > 1024) k = 1024;
      size_t xrow = (size_t)b*S_TOT + S0_ + k;
      *reinterpret_cast<short8v*>(&s_a[r*XPAD + c8]) =
          *reinterpret_cast<const short8v*>(xb + xrow*D_ + c8);
    }
    __syncthreads();

    f32x4 acc[2][2];
    #pragma unroll
    for(int i=0;i<2;++i)
      #pragma unroll
      for(int j=0;j<2;++j) acc[i][j] = (f32x4){0.f,0.f,0.f,0.f};

    const short* ar0 = &s_a[(wy*32 + colb)*XPAD];
    const short* ar1 = ar0 + 16*XPAD;
    const int ntg = (C0 >> 4) + wx*2;
    #pragma unroll
    for (int kt=0; kt<8; ++kt){
      short8v a0 = load_afrag(ar0, kt, khi);
      short8v a1 = load_afrag(ar1, kt, khi);
      short8v b0 = *reinterpret_cast<const short8v*>(WpV + ((size_t)((ntg+0)*8 + kt)*64 + lane)*8);
      short8v b1 = *reinterpret_cast<const short8v*>(WpV + ((size_t)((ntg+1)*8 + kt)*64 + lane)*8);
      acc[0][0] = __builtin_amdgcn_mfma_f32_16x16x32_bf16(a0, b0, acc[0][0], 0,0,0);
      acc[0][1] = __builtin_amdgcn_mfma_f32_16x16x32_bf16(a0, b1, acc[0][1], 0,0,0);
      acc[1][0] = __builtin_amdgcn_mfma_f32_16x16x32_bf16(a1, b0, acc[1][0], 0,0,0);
      acc[1][1] = __builtin_amdgcn_mfma_f32_16x16x32_bf16(a1, b1, acc[1][1], 0,0,0);
    }
    // silu + transpose into LDS [v_local][key_local]
    #pragma unroll
    for (int sj=0; sj<2; ++sj){
      int cl = wx*32 + sj*16 + colb;
      float bv = b_V[C0 + cl];
      #pragma unroll
      for (int si=0; si<2; ++si){
        #pragma unroll
        for (int r=0;r<4;++r){
          int rl = wy*32 + si*16 + ((lane>>4)<<2) + r;
          s_t[cl][rl] = f2bf(silu_f(acc[si][sj][r] + bv));
        }
      }
    }
    __syncthreads();
    {
      const int vt_l = tid >> 6;
      const int vloc = vt_l*16 + (lane & 15);
      const int krow = (lane>>4)<<2;
      #pragma unroll
      for (int kt=0; kt<2; ++kt){
        short8v f;
        #pragma unroll
        for (int j=0;j<8;++j){
          int kl = kt*32 + krow + (j&3) + ((j>>2)<<4);
          short v = s_t[vloc][kl];
          if (R0 + kl >= S1_) v = 0;
          f[j] = v;
        }
        size_t o = (((size_t)b*32 + (C0>>4) + vt_l)*(2*NT_) + 2*t + kt)*64 + lane;
        *reinterpret_cast<short8v*>(VtF + o*8) = f;
      }
    }
  } else {
    // ---------------- maskpack: 4 tiles per wave
    const int g0 = ((blk - 1600)*4 + wv)*4;
    #pragma unroll
    for (int j=0;j<4;++j){
      int tg = g0 + j;                 // wave-uniform
      if (tg >= NTILES) break;         // wave-uniform exit
      int row = tg / NT_;              // 0..8183
      int t   = tg - row*NT_;
      int b   = row / S0_;
      int q   = row - b*S0_;
      int key = t*64 + lane;
      unsigned char v = 0;
      if (key < S1_) v = amask[((size_t)(b*S_TOT + q))*S_TOT + S0_ + key];
      u64 bits = __ballot(v != 0);
      if (lane == 0) maskb[tg] = bits;
    }
  }
}

// ------- kernel 1c2: pack Z key rows -> A-fragment order (for flash QK) -----
__global__ __launch_bounds__(256) void k_packZ(const short* __restrict__ Zb,
                                               short* __restrict__ ZkF){
  const int lane = threadIdx.x & 63;
  const int w = blockIdx.x*4 + (threadIdx.x >> 6);
  if (w >= NB_*KT16_*4) return;
  const int b = w / (KT16_*4);
  const int rem = w - b*(KT16_*4);
  const int kt16 = rem >> 2, kt = rem & 3;
  int key = kt16*16 + (lane & 15); if (key > 1024) key = 1024;
  const short* zr = Zb + ((size_t)(b*S_TOT + S0_ + key))*DZ_ + kt*32 + ((lane>>4)<<2);
  short4v lo = *reinterpret_cast<const short4v*>(zr);
  short4v hi = *reinterpret_cast<const short4v*>(zr + 16);
  short8v f = {lo[0],lo[1],lo[2],lo[3],hi[0],hi[1],hi[2],hi[3]};
  *reinterpret_cast<short8v*>(ZkF + ((size_t)w*64 + lane)*8) = f;
}

// ------ kernel 2: fused flash attention + U-proj + out-proj + gating --------
// block = (batch b, 32-q pair: tiles A and B); 8 waves (512 thr).
#define SMEM_BYTES 103424
__global__ __launch_bounds__(512,2) void k_flash(
    const short* __restrict__ Zb, const short* __restrict__ ZkF,
    const short* __restrict__ VtF, const u64* __restrict__ maskb,
    const short* __restrict__ xb,
    const short* __restrict__ WpU, const float* __restrict__ b_U,
    const short* __restrict__ Wpo, const float* __restrict__ b_out,
    const short* __restrict__ Wpg, const float* __restrict__ b_gate,
    const float* __restrict__ seq, float* __restrict__ out,
    const int* __restrict__ heights,
    const float* __restrict__ os_g, const float* __restrict__ os_b,
    const float* __restrict__ embH)
{
  __shared__ __align__(16) char smem[SMEM_BYTES];
  __shared__ float  s_qh[32][12];
  __shared__ float  s_qb[32];
  __shared__ int    s_hk[NT_*64];
  __shared__ u64    s_mb[32][NT_];
  __shared__ float  s_mxA[8][16], s_mxB[8][16];
  __shared__ float  s_smA[8][16], s_smB[8][16];

  short8v (*s_pAl)[64] = reinterpret_cast<short8v(*)[64]>(smem);           // 17408
  short8v (*s_pAh)[64] = reinterpret_cast<short8v(*)[64]>(smem + 17408);   // ->34816
  short8v (*s_pBl)[64] = reinterpret_cast<short8v(*)[64]>(smem + 34816);   // ->52224
  short8v (*s_pBh)[64] = reinterpret_cast<short8v(*)[64]>(smem + 52224);   // ->69632
  short   (*s_qg)[132] = reinterpret_cast<short(*)[132]>(smem + 34816);    // overlay P_B
  short* sUV = reinterpret_cast<short*>(smem);            // 32*UPAD, overlay P_A
  short* sO  = reinterpret_cast<short*>(smem + 34816);    // 32*XPAD, overlay P_B
  short* sX  = reinterpret_cast<short*>(smem + 69632);    // 32*XPAD
  short* sR  = reinterpret_cast<short*>(smem + 86528);    // 32*XPAD -> 103424

  const int tid = threadIdx.x, lane = tid & 63, wv = tid >> 6;
  const int b  = blockIdx.x & 7;
  const int qp = blockIdx.x >> 3;
  const int q0 = qp * 32;

  // ---- stage x rows (bf16) and res rows (fp32 -> bf16), 32 rows each
  for (int c = tid; c < 32*32; c += 512){
    int r = c >> 5, c8 = (c & 31) << 3;
    int q = min(q0 + r, S0_-1);
    *reinterpret_cast<short8v*>(&sX[r*XPAD + c8]) =
        *reinterpret_cast<const short8v*>(xb + ((size_t)(b*S_TOT + q))*D_ + c8);
  }
  for (int c = tid; c < 32*64; c += 512){
    int r = c >> 6, c4 = (c & 63) << 2;
    int q = min(q0 + r, S0_-1);
    float4 f = *reinterpret_cast<const float4*>(seq + ((size_t)(b*S_TOT + q))*D_ + c4);
    short4v h = { f2bf(f.x), f2bf(f.y), f2bf(f.z), f2bf(f.w) };
    *reinterpret_cast<short4v*>(&sR[r*XPAD + c4]) = h;
  }

  // ---- Q prep: 16 threads per q-row, 8 dz each; 32 rows
  {
    int row = tid >> 4, part = tid & 15;
    int q = q0 + row; if (q > S0_-1) q = S0_-1;
    const short* zrow = Zb + ((size_t)(b*S_TOT + q))*DZ_ + part*8;
    float qb_acc = 0.f;
    float qh_acc[10];
    #pragma unroll
    for (int h=0;h<10;++h) qh_acc[h] = 0.f;
    #pragma unroll
    for (int e=0; e<8; ++e){
      int dz = part*8 + e;
      float z = bf2f(zrow[e]);
      float Q  = z*os_g[dz]      + os_b[dz];
      float Qp = z*os_g[DZ_+dz]  + os_b[DZ_+dz];
      s_qg[row][dz] = f2bf(Q * os_g[2*DZ_+dz]);
      qb_acc += Q * os_b[2*DZ_+dz];
      #pragma unroll
      for (int h=0;h<10;++h) qh_acc[h] += Qp * embH[h*DZ_ + dz];
    }
    #pragma unroll
    for (int m=1;m<16;m<<=1){
      qb_acc += __shfl_xor(qb_acc, m, 64);
      #pragma unroll
      for (int h=0;h<10;++h) qh_acc[h] += __shfl_xor(qh_acc[h], m, 64);
    }
    if (part == 0){
      s_qb[row] = qb_acc;
      #pragma unroll
      for (int h=0;h<10;++h) s_qh[row][h] = qh_acc[h];
    }
  }
  for (int k = tid; k < NT_*64; k += 512)
    s_hk[k] = (k < S1_) ? heights[b*S_TOT + S0_ + k] : 0;
  for (int idx = tid; idx < 32*NT_; idx += 512){
    int qq = idx / NT_, tt = idx - qq*NT_;
    int qr = min(q0 + qq, S0_-1);
    s_mb[qq][tt] = maskb[((size_t)(b*S0_ + qr))*NT_ + tt];
  }
  __syncthreads();

  const int qcol = lane & 15, khi = (lane>>4)<<2;
  const int hqA = heights[b*S_TOT + min(q0 + qcol,      S0_-1)];
  const int hqB = heights[b*S_TOT + min(q0 + 16 + qcol, S0_-1)];
  const float qbA = s_qb[qcol], qbB = s_qb[16 + qcol];

  short8v qgfA[4], qgfB[4];
  #pragma unroll
  for (int kt=0; kt<4; ++kt){
    qgfA[kt] = load_afrag(&s_qg[qcol][0],      kt, khi);
    qgfB[kt] = load_afrag(&s_qg[16 + qcol][0], kt, khi);
  }

  // ---- phase 1: QK for both tiles, shared A-frag loads; per-wave maxima
  f32x4 scA[3][4], scB[3][4];
  float tmA = -1e30f, tmB = -1e30f;
  #pragma unroll
  for (int it=0; it<3; ++it){
    const int t = it*8 + wv;
    if (t < NT_){
      u64 mbA = s_mb[qcol][t], mbB = s_mb[16 + qcol][t];
      #pragma unroll
      for (int st=0; st<4; ++st){
        f32x4 cA = (f32x4){0.f,0.f,0.f,0.f};
        f32x4 cB = (f32x4){0.f,0.f,0.f,0.f};
        #pragma unroll
        for (int kt=0; kt<4; ++kt){
          short8v a = *reinterpret_cast<const short8v*>(
              ZkF + (((size_t)(b*KT16_ + t*4 + st)*4 + kt)*64 + lane)*8);
          cA = __builtin_amdgcn_mfma_f32_16x16x32_bf16(a, qgfA[kt], cA, 0,0,0);
          cB = __builtin_amdgcn_mfma_f32_16x16x32_bf16(a, qgfB[kt], cB, 0,0,0);
        }
        int4 hk4 = *reinterpret_cast<const int4*>(&s_hk[t*64 + st*16 + khi]);
        #pragma unroll
        for (int r=0;r<4;++r){
          int hk = (&hk4.x)[r];
          int kl = st*16 + khi + r;
          int iA = min(max(hk - hqA, 1), 10) - 1;
          float vA = (cA[r] + qbA + s_qh[qcol][iA]) * SCALE_INV;
          vA = ((mbA >> kl) & 1ull) ? vA : -9999.f;
          cA[r] = vA; tmA = fmaxf(tmA, vA);
          int iB = min(max(hk - hqB, 1), 10) - 1;
          float vB = (cB[r] + qbB + s_qh[16 + qcol][iB]) * SCALE_INV;
          vB = ((mbB >> kl) & 1ull) ? vB : -9999.f;
          cB[r] = vB; tmB = fmaxf(tmB, vB);
        }
        scA[it][st] = cA; scB[it][st] = cB;
      }
    }
  }
  tmA = fmaxf(tmA, __shfl_xor(tmA, 16, 64));
  tmA = fmaxf(tmA, __shfl_xor(tmA, 32, 64));
  tmB = fmaxf(tmB, __shfl_xor(tmB, 16, 64));
  tmB = fmaxf(tmB, __shfl_xor(tmB, 32, 64));
  if (lane < 16){ s_mxA[wv][lane] = tmA; s_mxB[wv][lane] = tmB; }
  __syncthreads();

  // ---- phase 2: exact global max, exp, pack P for both tiles
  float mA = -1e30f, mB = -1e30f;
  #pragma unroll
  for (int w=0; w<8; ++w){
    mA = fmaxf(mA, s_mxA[w][qcol]);
    mB = fmaxf(mB, s_mxB[w][qcol]);
  }
  float lsA = 0.f, lsB = 0.f;
  #pragma unroll
  for (int it=0; it<3; ++it){
    const int t = it*8 + wv;
    if (t < NT_){
      #pragma unroll
      for (int st=0; st<4; ++st)
        #pragma unroll
        for (int r=0;r<4;++r){
          float pA = __expf(scA[it][st][r] - mA); lsA += pA; scA[it][st][r] = pA;
          float pB = __expf(scB[it][st][r] - mB); lsB += pB; scB[it][st][r] = pB;
        }
      short8v a0, a1, b0, b1;
      #pragma unroll
      for (int j=0;j<8;++j){
        a0[j] = f2bf(scA[it][(j>>2)][j&3]);
        a1[j] = f2bf(scA[it][2 + (j>>2)][j&3]);
        b0[j] = f2bf(scB[it][(j>>2)][j&3]);
        b1[j] = f2bf(scB[it][2 + (j>>2)][j&3]);
      }
      s_pAl[t][lane] = a0; s_pAh[t][lane] = a1;
      s_pBl[t][lane] = b0; s_pBh[t][lane] = b1;
    }
  }
  lsA += __shfl_xor(lsA, 16, 64); lsA += __shfl_xor(lsA, 32, 64);
  lsB += __shfl_xor(lsB, 16, 64); lsB += __shfl_xor(lsB, 32, 64);
  if (lane < 16){ s_smA[wv][lane] = lsA; s_smB[wv][lane] = lsB; }
  __syncthreads();

  // ---- phase 3: PV, each wave owns 64 v-cols, both tiles off shared V loads
  float lrA[4], lrB[4];
  #pragma unroll
  for (int r=0;r<4;++r){
    int qr = khi + r;
    float sa = 0.f, sb = 0.f;
    #pragma unroll
    for (int w=0; w<8; ++w){ sa += s_smA[w][qr]; sb += s_smB[w][qr]; }
    lrA[r] = sa; lrB[r] = sb;
  }
  f32x4 OA[4], OB[4];
  #pragma unroll
  for (int j=0;j<4;++j){ OA[j] = (f32x4){0.f,0.f,0.f,0.f}; OB[j] = (f32x4){0.f,0.f,0.f,0.f}; }
  for (int t=0; t<NT_; ++t){
    short8v pa0 = s_pAl[t][lane], pa1 = s_pAh[t][lane];
    short8v pb0 = s_pBl[t][lane], pb1 = s_pBh[t][lane];
    #pragma unroll
    for (int j=0;j<4;++j){
      size_t vb = ((size_t)b*32 + wv*4 + j)*(2*NT_) + 2*t;
      short8v v0 = *reinterpret_cast<const short8v*>(VtF + (vb*64 + lane)*8);
      short8v v1 = *reinterpret_cast<const short8v*>(VtF + ((vb+1)*64 + lane)*8);
      OA[j] = __builtin_amdgcn_mfma_f32_16x16x32_bf16(pa0, v0, OA[j], 0,0,0);
      OA[j] = __builtin_amdgcn_mfma_f32_16x16x32_bf16(pa1, v1, OA[j], 0,0,0);
      OB[j] = __builtin_amdgcn_mfma_f32_16x16x32_bf16(pb0, v0, OB[j], 0,0,0);
      OB[j] = __builtin_amdgcn_mfma_f32_16x16x32_bf16(pb1, v1, OB[j], 0,0,0);
    }
  }
  __syncthreads();   // P buffers die; sUV/sO region born

  // ---- U = silu(x @ W_U + b) for own 64 v-cols; uv = U*O/l -> sUV (both tiles)
  f32x4 auA[4], auB[4];
  #pragma unroll
  for (int j=0;j<4;++j){ auA[j] = (f32x4){0.f,0.f,0.f,0.f}; auB[j] = (f32x4){0.f,0.f,0.f,0.f}; }
  {
    const short* xrA = &sX[qcol*XPAD];
    const short* xrB = &sX[(16 + qcol)*XPAD];
    #pragma unroll
    for (int kt=0; kt<8; ++kt){
      short8v aA = load_afrag(xrA, kt, khi);
      short8v aB = load_afrag(xrB, kt, khi);
      #pragma unroll
      for (int j=0;j<4;++j){
        int nt = wv*4 + j;
        short8v bw = *reinterpret_cast<const short8v*>(WpU + ((size_t)(nt*8 + kt)*64 + lane)*8);
        auA[j] = __builtin_amdgcn_mfma_f32_16x16x32_bf16(aA, bw, auA[j], 0,0,0);
        auB[j] = __builtin_amdgcn_mfma_f32_16x16x32_bf16(aB, bw, auB[j], 0,0,0);
      }
    }
  }
  float invA[4], invB[4];
  #pragma unroll
  for (int r=0;r<4;++r){ invA[r] = 1.f / lrA[r]; invB[r] = 1.f / lrB[r]; }
  #pragma unroll
  for (int j=0;j<4;++j){
    int v = wv*64 + j*16 + qcol;
    float bu = b_U[v];
    #pragma unroll
    for (int r=0;r<4;++r){
      float uA = silu_f(auA[j][r] + bu);
      sUV[(khi + r)*UPAD + v] = f2bf(uA * OA[j][r] * invA[r]);
      float uB = silu_f(auB[j][r] + bu);
      sUV[(16 + khi + r)*UPAD + v] = f2bf(uB * OB[j][r] * invB[r]);
    }
  }
  __syncthreads();

  // ---- out-proj: o = UV @ W_out + b (each wave: 2 n-tiles, both tiles)
  f32x4 aoA[2], aoB[2];
  #pragma unroll
  for (int j=0;j<2;++j){ aoA[j] = (f32x4){0.f,0.f,0.f,0.f}; aoB[j] = (f32x4){0.f,0.f,0.f,0.f}; }
  {
    const short* uvA = &sUV[qcol*UPAD];
    const short* uvB = &sUV[(16 + qcol)*UPAD];
    #pragma unroll
    for (int kt=0; kt<16; ++kt){
      short8v aA = load_afrag(uvA, kt, khi);
      short8v aB = load_afrag(uvB, kt, khi);
      #pragma unroll
      for (int j=0;j<2;++j){
        int nt = wv*2 + j;
        short8v bw = *reinterpret_cast<const short8v*>(Wpo + ((size_t)(nt*16 + kt)*64 + lane)*8);
        aoA[j] = __builtin_amdgcn_mfma_f32_16x16x32_bf16(aA, bw, aoA[j], 0,0,0);
        aoB[j] = __builtin_amdgcn_mfma_f32_16x16x32_bf16(aB, bw, aoB[j], 0,0,0);
      }
    }
  }
  #pragma unroll
  for (int j=0;j<2;++j){
    int col = (wv*2+j)*16 + qcol;
    float bv = b_out[col];
    #pragma unroll
    for (int r=0;r<4;++r){
      aoA[j][r] += bv;  sO[(khi + r)*XPAD + col]      = f2bf(aoA[j][r]);
      aoB[j][r] += bv;  sO[(16 + khi + r)*XPAD + col] = f2bf(aoB[j][r]);
    }
  }
  __syncthreads();

  // ---- gate = sigmoid([o, res] @ W_gate + b); final mix + write, both tiles
  f32x4 agA[2], agB[2];
  #pragma unroll
  for (int j=0;j<2;++j){ agA[j] = (f32x4){0.f,0.f,0.f,0.f}; agB[j] = (f32x4){0.f,0.f,0.f,0.f}; }
  {
    const short* oA = &sO[qcol*XPAD];
    const short* oB = &sO[(16 + qcol)*XPAD];
    const short* rA = &sR[qcol*XPAD];
    const short* rB = &sR[(16 + qcol)*XPAD];
    #pragma unroll
    for (int kt=0; kt<8; ++kt){
      short8v aA = load_afrag(oA, kt, khi);
      short8v aB = load_afrag(oB, kt, khi);
      #pragma unroll
      for (int j=0;j<2;++j){
        int nt = wv*2 + j;
        short8v bw = *reinterpret_cast<const short8v*>(Wpg + ((size_t)(nt*16 + kt)*64 + lane)*8);
        agA[j] = __builtin_amdgcn_mfma_f32_16x16x32_bf16(aA, bw, agA[j], 0,0,0);
        agB[j] = __builtin_amdgcn_mfma_f32_16x16x32_bf16(aB, bw, agB[j], 0,0,0);
      }
    }
    #pragma unroll
    for (int kt=0; kt<8; ++kt){
      short8v aA = load_afrag(rA, kt, khi);
      short8v aB = load_afrag(rB, kt, khi);
      #pragma unroll
      for (int j=0;j<2;++j){
        int nt = wv*2 + j;
        short8v bw = *reinterpret_cast<const short8v*>(Wpg + ((size_t)(nt*16 + 8 + kt)*64 + lane)*8);
        agA[j] = __builtin_amdgcn_mfma_f32_16x16x32_bf16(aA, bw, agA[j], 0,0,0);
        agB[j] = __builtin_amdgcn_mfma_f32_16x16x32_bf16(aB, bw, agB[j], 0,0,0);
      }
    }
  }
  #pragma unroll
  for (int j=0;j<2;++j){
    int col = (wv*2+j)*16 + qcol;
    float bg = b_gate[col];
    #pragma unroll
    for (int r=0;r<4;++r){
      int qA = q0 + khi + r;
      if (qA < S0_){
        float res = seq[((size_t)(b*S_TOT + qA))*D_ + col];
        float g = 1.f/(1.f + __expf(-(agA[j][r] + bg)));
        out[((size_t)(b*S_TOT + qA))*D_ + col] = g*aoA[j][r] + (1.f-g)*res;
      }
      int qB = q0 + 16 + khi + r;
      if (qB < S0_){
        float res = seq[((size_t)(b*S_TOT + qB))*D_ + col];
        float g = 1.f/(1.f + __expf(-(agB[j][r] + bg)));
        out[((size_t)(b*S_TOT + qB))*D_ + col] = g*aoB[j][r] + (1.f-g)*res;
      }
    }
  }
}

extern "C" void kernel_launch(void* const* d_in, const int* in_sizes, int n_in,
                              void* d_out, int out_size, void* d_ws, size_t ws_size,
                              hipStream_t stream)
{
  const float* seq    = (const float*)d_in[0];
  const unsigned char* amask = (const unsigned char*)d_in[1];
  const int*   heights= (const int*)d_in[2];
  const float* W_init = (const float*)d_in[3];
  const float* b_init = (const float*)d_in[4];
  const float* ln_g   = (const float*)d_in[5];
  const float* ln_b   = (const float*)d_in[6];
  const float* W_U    = (const float*)d_in[7];
  const float* b_U    = (const float*)d_in[8];
  const float* W_V    = (const float*)d_in[9];
  const float* b_V    = (const float*)d_in[10];
  const float* W_Z    = (const float*)d_in[11];
  const float* b_Z    = (const float*)d_in[12];
  const float* os_g   = (const float*)d_in[13];
  const float* os_b   = (const float*)d_in[14];
  const float* embH   = (const float*)d_in[15];
  const float* W_out  = (const float*)d_in[16];
  const float* b_out  = (const float*)d_in[17];
  const float* W_gate = (const float*)d_in[18];
  const float* b_gate = (const float*)d_in[19];
  float* out = (float*)d_out;

  char* w = (char*)d_ws;
  short* Zb  = (short*)w;                w += (size_t)16512*128*2;         // bf16 Z row-major
  short* VtF = (short*)w;                w += (size_t)8*32*(2*NT_)*64*8*2; // V B-frags
  short* ZkF = (short*)w;                w += (size_t)NB_*KT16_*4*64*8*2;  // Z-key A-frags
  short* xb  = (short*)w;                w += (size_t)16384*256*2;
  u64*  maskb = (u64*)w;                 w += (size_t)NB_*S0_*NT_*8;
  short* WpI = (short*)w;                w += (size_t)65536*2;
  short* WpU = (short*)w;                w += (size_t)131072*2;
  short* WpV = (short*)w;                w += (size_t)131072*2;
  short* WpZ = (short*)w;                w += (size_t)32768*2;
  short* WpO = (short*)w;                w += (size_t)131072*2;
  short* WpG = (short*)w;                w += (size_t)131072*2;

  hipLaunchKernelGGL(k_prep, dim3(304), dim3(256), 0, stream,
      W_init, W_U, W_V, W_Z, W_out, W_gate,
      WpI, WpU, WpV, WpZ, WpO, WpG);

  hipLaunchKernelGGL(k_x, dim3(256), dim3(256), 0, stream,
      seq, WpI, b_init, ln_g, ln_b, xb, out);

  hipLaunchKernelGGL(k_gemmZV, dim3(1600 + MP_BLOCKS), dim3(256), 0, stream,
      xb, WpZ, b_Z, Zb, WpV, b_V, VtF, amask, maskb);

  hipLaunchKernelGGL(k_packZ, dim3((NB_*KT16_*4 + 3)/4), dim3(256), 0, stream, Zb, ZkF);

  hipLaunchKernelGGL(k_flash, dim3(256), dim3(512), 0, stream,
      Zb, ZkF, VtF, maskb, xb, WpU, b_U, WpO, b_out, WpG, b_gate,
      seq, out, heights, os_g, os_b, embH);
}

// Round 16
// 97.651 us; speedup vs baseline: 1.1106x; 1.1106x over previous
//
#include <hip/hip_runtime.h>
#include <cstdint>
#include <cstddef>

#define S_TOT 2048
#define S0_   1023
#define S1_   1025
#define D_    256
#define D2_   512
#define DZ_   128
#define NB_   8
#define NT_   17            // 17 * 64 padded keys = 1088
#define KT16_ 68            // 17*4 16-key groups
#define SCALE_INV (1.0f/16.0f)
#define XPAD  264           // 256 + 8 bf16 pad
#define UPAD  520           // 512 + 8 bf16 pad
#define NTILES (NB_*S0_*NT_)        // 139128 mask tiles
#define MP_BLOCKS ((NTILES + 15)/16) // 16 tiles/block (4 per wave)

typedef __attribute__((ext_vector_type(8))) short short8v;
typedef __attribute__((ext_vector_type(4))) short short4v;
typedef __attribute__((ext_vector_type(4))) float f32x4;
typedef unsigned long long u64;

__device__ __forceinline__ short f2bf(float f){
  unsigned u = __float_as_uint(f);
  unsigned r = (u + 0x7FFFu + ((u >> 16) & 1u)) >> 16;
  return (short)r;
}
__device__ __forceinline__ float bf2f(short s){
  return __uint_as_float(((unsigned)(unsigned short)s) << 16);
}
__device__ __forceinline__ float silu_f(float x){ return x / (1.f + __expf(-x)); }

// A/B fragment load from a row-major row (verified layout, round 1):
// elems 0..3: k = kt*32 + khi + j ; elems 4..7: +16
__device__ __forceinline__ short8v load_afrag(const short* arow, int kt, int khi){
  short4v lo = *reinterpret_cast<const short4v*>(arow + kt*32 + khi);
  short4v hi = *reinterpret_cast<const short4v*>(arow + kt*32 + khi + 16);
  short8v r = {lo[0],lo[1],lo[2],lo[3],hi[0],hi[1],hi[2],hi[3]};
  return r;
}

// ------- k_prep: ALL weight packs + mask bitmask pack in ONE launch ---------
__global__ __launch_bounds__(256) void k_prep(
    const float* __restrict__ W_init, const float* __restrict__ W_U,
    const float* __restrict__ W_V,    const float* __restrict__ W_Z,
    const float* __restrict__ W_out,  const float* __restrict__ W_gate,
    short* __restrict__ WpI, short* __restrict__ WpU, short* __restrict__ WpV,
    short* __restrict__ WpZ, short* __restrict__ WpO, short* __restrict__ WpG,
    const unsigned char* __restrict__ amask, u64* __restrict__ maskb)
{
  const int blk = blockIdx.x;
  if (blk < 304){
    const float* W; short* dst; int K, N, base;
    if      (blk <  32){ W=W_init; dst=WpI; K=256; N=256; base=0;   }
    else if (blk <  96){ W=W_U;    dst=WpU; K=256; N=512; base=32;  }
    else if (blk < 160){ W=W_V;    dst=WpV; K=256; N=512; base=96;  }
    else if (blk < 176){ W=W_Z;    dst=WpZ; K=256; N=128; base=160; }
    else if (blk < 240){ W=W_out;  dst=WpO; K=512; N=256; base=176; }
    else               { W=W_gate; dst=WpG; K=512; N=256; base=240; }
    const int wv = threadIdx.x >> 6, lane = threadIdx.x & 63;
    const int KT = K >> 5;
    const int tile = (blk - base)*4 + wv;
    const int nt = tile / KT, kt = tile - nt*KT;
    const int n = nt*16 + (lane & 15);
    const int kbase = kt*32 + ((lane>>4)<<2);
    short8v v;
    #pragma unroll
    for (int j=0;j<8;++j){
      int k = kbase + (j&3) + ((j>>2)<<4);
      v[j] = f2bf(W[(size_t)k*N + n]);
    }
    *reinterpret_cast<short8v*>(dst + ((size_t)tile*64 + lane)*8) = v;
  } else {
    const int lane = threadIdx.x & 63;
    const int g0 = ((blk - 304)*4 + (threadIdx.x >> 6))*4;   // first tile of wave
    #pragma unroll
    for (int j=0;j<4;++j){
      int tg = g0 + j;                 // wave-uniform
      if (tg >= NTILES) break;         // wave-uniform exit
      int row = tg / NT_;              // 0..8183
      int t   = tg - row*NT_;
      int b   = row / S0_;
      int q   = row - b*S0_;
      int key = t*64 + lane;
      unsigned char v = 0;
      if (key < S1_) v = amask[((size_t)(b*S_TOT + q))*S_TOT + S0_ + key];
      u64 bits = __ballot(v != 0);
      if (lane == 0) maskb[tg] = bits;
    }
  }
}

// ---------------- kernel 1a: x = LN(seq@W_init + b) -> bf16; tail rows->out -
__global__ __launch_bounds__(256) void k_x(
    const float* __restrict__ seq, const short* __restrict__ Wp,
    const float* __restrict__ b_init,
    const float* __restrict__ ln_g, const float* __restrict__ ln_b,
    short* __restrict__ xb, float* __restrict__ out)
{
  __shared__ short s_a[64*XPAD];
  const int tid = threadIdx.x, lane = tid & 63, wv = tid >> 6;
  const int R0 = blockIdx.x * 64;
  const int colb = lane & 15, khi = (lane>>4)<<2;

  for (int c = tid; c < 64*64; c += 256){
    int row = c >> 6, c4 = (c & 63) << 2;
    int g = R0 + row;
    float4 f = *reinterpret_cast<const float4*>(seq + (size_t)g*D_ + c4);
    short4v h = { f2bf(f.x), f2bf(f.y), f2bf(f.z), f2bf(f.w) };
    *reinterpret_cast<short4v*>(&s_a[row*XPAD + c4]) = h;
    if ((g & 2047) >= S0_)           // passthrough tail rows
      *reinterpret_cast<float4*>(out + (size_t)g*D_ + c4) = f;
  }
  __syncthreads();

  f32x4 acc[16];
  #pragma unroll
  for (int nt=0;nt<16;++nt) acc[nt] = (f32x4){0.f,0.f,0.f,0.f};

  const short* arow = &s_a[(wv*16 + colb)*XPAD];
  #pragma unroll
  for (int kt=0; kt<8; ++kt){
    short8v a = load_afrag(arow, kt, khi);
    #pragma unroll
    for (int nt=0; nt<16; ++nt){
      short8v b = *reinterpret_cast<const short8v*>(Wp + ((size_t)(nt*8 + kt)*64 + lane)*8);
      acc[nt] = __builtin_amdgcn_mfma_f32_16x16x32_bf16(a, b, acc[nt], 0, 0, 0);
    }
  }

  float sum[4] = {0.f,0.f,0.f,0.f};
  #pragma unroll
  for (int nt=0; nt<16; ++nt){
    float bv = b_init[nt*16 + colb];
    #pragma unroll
    for (int r=0;r<4;++r){ acc[nt][r] += bv; sum[r] += acc[nt][r]; }
  }
  #pragma unroll
  for (int r=0;r<4;++r){
    #pragma unroll
    for (int m=1;m<16;m<<=1) sum[r] += __shfl_xor(sum[r], m, 64);
    sum[r] *= (1.f/256.f);
  }
  float var[4] = {0.f,0.f,0.f,0.f};
  #pragma unroll
  for (int nt=0; nt<16; ++nt)
    #pragma unroll
    for (int r=0;r<4;++r){ float d = acc[nt][r]-sum[r]; var[r] += d*d; }
  #pragma unroll
  for (int r=0;r<4;++r){
    #pragma unroll
    for (int m=1;m<16;m<<=1) var[r] += __shfl_xor(var[r], m, 64);
    var[r] = rsqrtf(var[r]*(1.f/256.f) + 1e-5f);
  }
  #pragma unroll
  for (int nt=0; nt<16; ++nt){
    int col = nt*16 + colb;
    float g = ln_g[col], bb = ln_b[col];
    #pragma unroll
    for (int r=0;r<4;++r){
      float xn = (acc[nt][r]-sum[r])*var[r]*g + bb;
      s_a[(wv*16 + ((lane>>4)<<2) + r)*XPAD + col] = f2bf(xn);
    }
  }
  __syncthreads();
  for (int c = tid; c < 64*32; c += 256){
    int row = c >> 5, c8 = (c & 31) << 3;
    *reinterpret_cast<short8v*>(xb + (size_t)(R0+row)*D_ + c8) =
        *reinterpret_cast<const short8v*>(&s_a[row*XPAD + c8]);
  }
}

// ---- k_gemmZV: Z-gemm (blocks [0,512)) + V-gemm (blocks [512,1600)) --------
__global__ __launch_bounds__(256) void k_gemmZV(
    const short* __restrict__ xb,
    const short* __restrict__ WpZ, const float* __restrict__ b_Z,
    short* __restrict__ Zb,
    const short* __restrict__ WpV, const float* __restrict__ b_V,
    short* __restrict__ VtF)
{
  __shared__ short s_a[64*XPAD];
  __shared__ short s_t[64][72];
  const int blk = blockIdx.x;
  const int tid = threadIdx.x, lane = tid & 63, wv = tid >> 6;
  const int wy = wv >> 1, wx = wv & 1;
  const int colb = lane & 15, khi = (lane>>4)<<2;

  if (blk < 512){
    const int R0 = (blk >> 1) * 64;
    const int C0 = (blk & 1) * 64;

    for (int c = tid; c < 64*32; c += 256){
      int r = c >> 5, c8 = (c & 31) << 3;
      size_t xrow = (size_t)(R0 + r);
      *reinterpret_cast<short8v*>(&s_a[r*XPAD + c8]) =
          *reinterpret_cast<const short8v*>(xb + xrow*D_ + c8);
    }
    __syncthreads();

    f32x4 acc[2][2];
    #pragma unroll
    for(int i=0;i<2;++i)
      #pragma unroll
      for(int j=0;j<2;++j) acc[i][j] = (f32x4){0.f,0.f,0.f,0.f};

    const short* ar0 = &s_a[(wy*32 + colb)*XPAD];
    const short* ar1 = ar0 + 16*XPAD;
    const int ntg = (C0 >> 4) + wx*2;
    #pragma unroll
    for (int kt=0; kt<8; ++kt){
      short8v a0 = load_afrag(ar0, kt, khi);
      short8v a1 = load_afrag(ar1, kt, khi);
      short8v b0 = *reinterpret_cast<const short8v*>(WpZ + ((size_t)((ntg+0)*8 + kt)*64 + lane)*8);
      short8v b1 = *reinterpret_cast<const short8v*>(WpZ + ((size_t)((ntg+1)*8 + kt)*64 + lane)*8);
      acc[0][0] = __builtin_amdgcn_mfma_f32_16x16x32_bf16(a0, b0, acc[0][0], 0,0,0);
      acc[0][1] = __builtin_amdgcn_mfma_f32_16x16x32_bf16(a0, b1, acc[0][1], 0,0,0);
      acc[1][0] = __builtin_amdgcn_mfma_f32_16x16x32_bf16(a1, b0, acc[1][0], 0,0,0);
      acc[1][1] = __builtin_amdgcn_mfma_f32_16x16x32_bf16(a1, b1, acc[1][1], 0,0,0);
    }
    #pragma unroll
    for (int sj=0; sj<2; ++sj){
      int col = C0 + wx*32 + sj*16 + colb;
      float bv = b_Z[col];
      #pragma unroll
      for (int si=0; si<2; ++si){
        #pragma unroll
        for (int r=0;r<4;++r){
          int orow = R0 + wy*32 + si*16 + ((lane>>4)<<2) + r;
          Zb[(size_t)orow*DZ_ + col] = f2bf(silu_f(acc[si][sj][r] + bv));
        }
      }
    }
  } else {
    const int idx = blk - 512;
    const int t   = idx % 17;
    const int rest= idx / 17;
    const int C0  = (rest & 7) * 64;
    const int b   = rest >> 3;
    const int R0  = t * 64;

    for (int c = tid; c < 64*32; c += 256){
      int r = c >> 5, c8 = (c & 31) << 3;
      int k = R0 + r; if (k > 1024) k = 1024;
      size_t xrow = (size_t)b*S_TOT + S0_ + k;
      *reinterpret_cast<short8v*>(&s_a[r*XPAD + c8]) =
          *reinterpret_cast<const short8v*>(xb + xrow*D_ + c8);
    }
    __syncthreads();

    f32x4 acc[2][2];
    #pragma unroll
    for(int i=0;i<2;++i)
      #pragma unroll
      for(int j=0;j<2;++j) acc[i][j] = (f32x4){0.f,0.f,0.f,0.f};

    const short* ar0 = &s_a[(wy*32 + colb)*XPAD];
    const short* ar1 = ar0 + 16*XPAD;
    const int ntg = (C0 >> 4) + wx*2;
    #pragma unroll
    for (int kt=0; kt<8; ++kt){
      short8v a0 = load_afrag(ar0, kt, khi);
      short8v a1 = load_afrag(ar1, kt, khi);
      short8v b0 = *reinterpret_cast<const short8v*>(WpV + ((size_t)((ntg+0)*8 + kt)*64 + lane)*8);
      short8v b1 = *reinterpret_cast<const short8v*>(WpV + ((size_t)((ntg+1)*8 + kt)*64 + lane)*8);
      acc[0][0] = __builtin_amdgcn_mfma_f32_16x16x32_bf16(a0, b0, acc[0][0], 0,0,0);
      acc[0][1] = __builtin_amdgcn_mfma_f32_16x16x32_bf16(a0, b1, acc[0][1], 0,0,0);
      acc[1][0] = __builtin_amdgcn_mfma_f32_16x16x32_bf16(a1, b0, acc[1][0], 0,0,0);
      acc[1][1] = __builtin_amdgcn_mfma_f32_16x16x32_bf16(a1, b1, acc[1][1], 0,0,0);
    }
    // silu + transpose into LDS [v_local][key_local]
    #pragma unroll
    for (int sj=0; sj<2; ++sj){
      int cl = wx*32 + sj*16 + colb;
      float bv = b_V[C0 + cl];
      #pragma unroll
      for (int si=0; si<2; ++si){
        #pragma unroll
        for (int r=0;r<4;++r){
          int rl = wy*32 + si*16 + ((lane>>4)<<2) + r;
          s_t[cl][rl] = f2bf(silu_f(acc[si][sj][r] + bv));
        }
      }
    }
    __syncthreads();
    {
      const int vt_l = tid >> 6;
      const int vloc = vt_l*16 + (lane & 15);
      const int krow = (lane>>4)<<2;
      #pragma unroll
      for (int kt=0; kt<2; ++kt){
        short8v f;
        #pragma unroll
        for (int j=0;j<8;++j){
          int kl = kt*32 + krow + (j&3) + ((j>>2)<<4);
          short v = s_t[vloc][kl];
          if (R0 + kl >= S1_) v = 0;
          f[j] = v;
        }
        size_t o = (((size_t)b*32 + (C0>>4) + vt_l)*(2*NT_) + 2*t + kt)*64 + lane;
        *reinterpret_cast<short8v*>(VtF + o*8) = f;
      }
    }
  }
}

// ------- kernel 1c2: pack Z key rows -> A-fragment order (for flash QK) -----
__global__ __launch_bounds__(256) void k_packZ(const short* __restrict__ Zb,
                                               short* __restrict__ ZkF){
  const int lane = threadIdx.x & 63;
  const int w = blockIdx.x*4 + (threadIdx.x >> 6);
  if (w >= NB_*KT16_*4) return;
  const int b = w / (KT16_*4);
  const int rem = w - b*(KT16_*4);
  const int kt16 = rem >> 2, kt = rem & 3;
  int key = kt16*16 + (lane & 15); if (key > 1024) key = 1024;
  const short* zr = Zb + ((size_t)(b*S_TOT + S0_ + key))*DZ_ + kt*32 + ((lane>>4)<<2);
  short4v lo = *reinterpret_cast<const short4v*>(zr);
  short4v hi = *reinterpret_cast<const short4v*>(zr + 16);
  short8v f = {lo[0],lo[1],lo[2],lo[3],hi[0],hi[1],hi[2],hi[3]};
  *reinterpret_cast<short8v*>(ZkF + ((size_t)w*64 + lane)*8) = f;
}

// ------ kernel 2: fused flash attention + U-proj + out-proj + gating --------
// block = (batch b, 32-q pair: tiles A and B); 8 waves (512 thr).
#define SMEM_BYTES 103424
__global__ __launch_bounds__(512,2) void k_flash(
    const short* __restrict__ Zb, const short* __restrict__ ZkF,
    const short* __restrict__ VtF, const u64* __restrict__ maskb,
    const short* __restrict__ xb,
    const short* __restrict__ WpU, const float* __restrict__ b_U,
    const short* __restrict__ Wpo, const float* __restrict__ b_out,
    const short* __restrict__ Wpg, const float* __restrict__ b_gate,
    const float* __restrict__ seq, float* __restrict__ out,
    const int* __restrict__ heights,
    const float* __restrict__ os_g, const float* __restrict__ os_b,
    const float* __restrict__ embH)
{
  __shared__ __align__(16) char smem[SMEM_BYTES];
  __shared__ float  s_qh[32][12];
  __shared__ float  s_qb[32];
  __shared__ int    s_hk[NT_*64];
  __shared__ u64    s_mb[32][NT_];
  __shared__ float  s_mxA[8][16], s_mxB[8][16];
  __shared__ float  s_smA[8][16], s_smB[8][16];

  short8v (*s_pAl)[64] = reinterpret_cast<short8v(*)[64]>(smem);           // 17408
  short8v (*s_pAh)[64] = reinterpret_cast<short8v(*)[64]>(smem + 17408);   // ->34816
  short8v (*s_pBl)[64] = reinterpret_cast<short8v(*)[64]>(smem + 34816);   // ->52224
  short8v (*s_pBh)[64] = reinterpret_cast<short8v(*)[64]>(smem + 52224);   // ->69632
  short   (*s_qg)[132] = reinterpret_cast<short(*)[132]>(smem + 34816);    // overlay P_B
  short* sUV = reinterpret_cast<short*>(smem);            // 32*UPAD, overlay P_A
  short* sO  = reinterpret_cast<short*>(smem + 34816);    // 32*XPAD, overlay P_B
  short* sX  = reinterpret_cast<short*>(smem + 69632);    // 32*XPAD
  short* sR  = reinterpret_cast<short*>(smem + 86528);    // 32*XPAD -> 103424

  const int tid = threadIdx.x, lane = tid & 63, wv = tid >> 6;
  const int b  = blockIdx.x & 7;
  const int qp = blockIdx.x >> 3;
  const int q0 = qp * 32;

  // ---- stage x rows (bf16) and res rows (fp32 -> bf16), 32 rows each
  for (int c = tid; c < 32*32; c += 512){
    int r = c >> 5, c8 = (c & 31) << 3;
    int q = min(q0 + r, S0_-1);
    *reinterpret_cast<short8v*>(&sX[r*XPAD + c8]) =
        *reinterpret_cast<const short8v*>(xb + ((size_t)(b*S_TOT + q))*D_ + c8);
  }
  for (int c = tid; c < 32*64; c += 512){
    int r = c >> 6, c4 = (c & 63) << 2;
    int q = min(q0 + r, S0_-1);
    float4 f = *reinterpret_cast<const float4*>(seq + ((size_t)(b*S_TOT + q))*D_ + c4);
    short4v h = { f2bf(f.x), f2bf(f.y), f2bf(f.z), f2bf(f.w) };
    *reinterpret_cast<short4v*>(&sR[r*XPAD + c4]) = h;
  }

  // ---- Q prep: 16 threads per q-row, 8 dz each; 32 rows
  {
    int row = tid >> 4, part = tid & 15;
    int q = q0 + row; if (q > S0_-1) q = S0_-1;
    const short* zrow = Zb + ((size_t)(b*S_TOT + q))*DZ_ + part*8;
    float qb_acc = 0.f;
    float qh_acc[10];
    #pragma unroll
    for (int h=0;h<10;++h) qh_acc[h] = 0.f;
    #pragma unroll
    for (int e=0; e<8; ++e){
      int dz = part*8 + e;
      float z = bf2f(zrow[e]);
      float Q  = z*os_g[dz]      + os_b[dz];
      float Qp = z*os_g[DZ_+dz]  + os_b[DZ_+dz];
      s_qg[row][dz] = f2bf(Q * os_g[2*DZ_+dz]);
      qb_acc += Q * os_b[2*DZ_+dz];
      #pragma unroll
      for (int h=0;h<10;++h) qh_acc[h] += Qp * embH[h*DZ_ + dz];
    }
    #pragma unroll
    for (int m=1;m<16;m<<=1){
      qb_acc += __shfl_xor(qb_acc, m, 64);
      #pragma unroll
      for (int h=0;h<10;++h) qh_acc[h] += __shfl_xor(qh_acc[h], m, 64);
    }
    if (part == 0){
      s_qb[row] = qb_acc;
      #pragma unroll
      for (int h=0;h<10;++h) s_qh[row][h] = qh_acc[h];
    }
  }
  for (int k = tid; k < NT_*64; k += 512)
    s_hk[k] = (k < S1_) ? heights[b*S_TOT + S0_ + k] : 0;
  for (int idx = tid; idx < 32*NT_; idx += 512){
    int qq = idx / NT_, tt = idx - qq*NT_;
    int qr = min(q0 + qq, S0_-1);
    s_mb[qq][tt] = maskb[((size_t)(b*S0_ + qr))*NT_ + tt];
  }
  __syncthreads();

  const int qcol = lane & 15, khi = (lane>>4)<<2;
  const int hqA = heights[b*S_TOT + min(q0 + qcol,      S0_-1)];
  const int hqB = heights[b*S_TOT + min(q0 + 16 + qcol, S0_-1)];
  const float qbA = s_qb[qcol], qbB = s_qb[16 + qcol];

  short8v qgfA[4], qgfB[4];
  #pragma unroll
  for (int kt=0; kt<4; ++kt){
    qgfA[kt] = load_afrag(&s_qg[qcol][0],      kt, khi);
    qgfB[kt] = load_afrag(&s_qg[16 + qcol][0], kt, khi);
  }

  // ---- phase 1: QK for both tiles, shared A-frag loads; per-wave maxima
  f32x4 scA[3][4], scB[3][4];
  float tmA = -1e30f, tmB = -1e30f;
  #pragma unroll
  for (int it=0; it<3; ++it){
    const int t = it*8 + wv;
    if (t < NT_){
      u64 mbA = s_mb[qcol][t], mbB = s_mb[16 + qcol][t];
      #pragma unroll
      for (int st=0; st<4; ++st){
        f32x4 cA = (f32x4){0.f,0.f,0.f,0.f};
        f32x4 cB = (f32x4){0.f,0.f,0.f,0.f};
        #pragma unroll
        for (int kt=0; kt<4; ++kt){
          short8v a = *reinterpret_cast<const short8v*>(
              ZkF + (((size_t)(b*KT16_ + t*4 + st)*4 + kt)*64 + lane)*8);
          cA = __builtin_amdgcn_mfma_f32_16x16x32_bf16(a, qgfA[kt], cA, 0,0,0);
          cB = __builtin_amdgcn_mfma_f32_16x16x32_bf16(a, qgfB[kt], cB, 0,0,0);
        }
        int4 hk4 = *reinterpret_cast<const int4*>(&s_hk[t*64 + st*16 + khi]);
        #pragma unroll
        for (int r=0;r<4;++r){
          int hk = (&hk4.x)[r];
          int kl = st*16 + khi + r;
          int iA = min(max(hk - hqA, 1), 10) - 1;
          float vA = (cA[r] + qbA + s_qh[qcol][iA]) * SCALE_INV;
          vA = ((mbA >> kl) & 1ull) ? vA : -9999.f;
          cA[r] = vA; tmA = fmaxf(tmA, vA);
          int iB = min(max(hk - hqB, 1), 10) - 1;
          float vB = (cB[r] + qbB + s_qh[16 + qcol][iB]) * SCALE_INV;
          vB = ((mbB >> kl) & 1ull) ? vB : -9999.f;
          cB[r] = vB; tmB = fmaxf(tmB, vB);
        }
        scA[it][st] = cA; scB[it][st] = cB;
      }
    }
  }
  tmA = fmaxf(tmA, __shfl_xor(tmA, 16, 64));
  tmA = fmaxf(tmA, __shfl_xor(tmA, 32, 64));
  tmB = fmaxf(tmB, __shfl_xor(tmB, 16, 64));
  tmB = fmaxf(tmB, __shfl_xor(tmB, 32, 64));
  if (lane < 16){ s_mxA[wv][lane] = tmA; s_mxB[wv][lane] = tmB; }
  __syncthreads();

  // ---- phase 2: exact global max, exp, pack P for both tiles
  float mA = -1e30f, mB = -1e30f;
  #pragma unroll
  for (int w=0; w<8; ++w){
    mA = fmaxf(mA, s_mxA[w][qcol]);
    mB = fmaxf(mB, s_mxB[w][qcol]);
  }
  float lsA = 0.f, lsB = 0.f;
  #pragma unroll
  for (int it=0; it<3; ++it){
    const int t = it*8 + wv;
    if (t < NT_){
      #pragma unroll
      for (int st=0; st<4; ++st)
        #pragma unroll
        for (int r=0;r<4;++r){
          float pA = __expf(scA[it][st][r] - mA); lsA += pA; scA[it][st][r] = pA;
          float pB = __expf(scB[it][st][r] - mB); lsB += pB; scB[it][st][r] = pB;
        }
      short8v a0, a1, b0, b1;
      #pragma unroll
      for (int j=0;j<8;++j){
        a0[j] = f2bf(scA[it][(j>>2)][j&3]);
        a1[j] = f2bf(scA[it][2 + (j>>2)][j&3]);
        b0[j] = f2bf(scB[it][(j>>2)][j&3]);
        b1[j] = f2bf(scB[it][2 + (j>>2)][j&3]);
      }
      s_pAl[t][lane] = a0; s_pAh[t][lane] = a1;
      s_pBl[t][lane] = b0; s_pBh[t][lane] = b1;
    }
  }
  lsA += __shfl_xor(lsA, 16, 64); lsA += __shfl_xor(lsA, 32, 64);
  lsB += __shfl_xor(lsB, 16, 64); lsB += __shfl_xor(lsB, 32, 64);
  if (lane < 16){ s_smA[wv][lane] = lsA; s_smB[wv][lane] = lsB; }
  __syncthreads();

  // ---- phase 3: PV, each wave owns 64 v-cols, both tiles off shared V loads
  float lrA[4], lrB[4];
  #pragma unroll
  for (int r=0;r<4;++r){
    int qr = khi + r;
    float sa = 0.f, sb = 0.f;
    #pragma unroll
    for (int w=0; w<8; ++w){ sa += s_smA[w][qr]; sb += s_smB[w][qr]; }
    lrA[r] = sa; lrB[r] = sb;
  }
  f32x4 OA[4], OB[4];
  #pragma unroll
  for (int j=0;j<4;++j){ OA[j] = (f32x4){0.f,0.f,0.f,0.f}; OB[j] = (f32x4){0.f,0.f,0.f,0.f}; }
  for (int t=0; t<NT_; ++t){
    short8v pa0 = s_pAl[t][lane], pa1 = s_pAh[t][lane];
    short8v pb0 = s_pBl[t][lane], pb1 = s_pBh[t][lane];
    #pragma unroll
    for (int j=0;j<4;++j){
      size_t vb = ((size_t)b*32 + wv*4 + j)*(2*NT_) + 2*t;
      short8v v0 = *reinterpret_cast<const short8v*>(VtF + (vb*64 + lane)*8);
      short8v v1 = *reinterpret_cast<const short8v*>(VtF + ((vb+1)*64 + lane)*8);
      OA[j] = __builtin_amdgcn_mfma_f32_16x16x32_bf16(pa0, v0, OA[j], 0,0,0);
      OA[j] = __builtin_amdgcn_mfma_f32_16x16x32_bf16(pa1, v1, OA[j], 0,0,0);
      OB[j] = __builtin_amdgcn_mfma_f32_16x16x32_bf16(pb0, v0, OB[j], 0,0,0);
      OB[j] = __builtin_amdgcn_mfma_f32_16x16x32_bf16(pb1, v1, OB[j], 0,0,0);
    }
  }
  __syncthreads();   // P buffers die; sUV/sO region born

  // ---- U = silu(x @ W_U + b) for own 64 v-cols; uv = U*O/l -> sUV (both tiles)
  f32x4 auA[4], auB[4];
  #pragma unroll
  for (int j=0;j<4;++j){ auA[j] = (f32x4){0.f,0.f,0.f,0.f}; auB[j] = (f32x4){0.f,0.f,0.f,0.f}; }
  {
    const short* xrA = &sX[qcol*XPAD];
    const short* xrB = &sX[(16 + qcol)*XPAD];
    #pragma unroll
    for (int kt=0; kt<8; ++kt){
      short8v aA = load_afrag(xrA, kt, khi);
      short8v aB = load_afrag(xrB, kt, khi);
      #pragma unroll
      for (int j=0;j<4;++j){
        int nt = wv*4 + j;
        short8v bw = *reinterpret_cast<const short8v*>(WpU + ((size_t)(nt*8 + kt)*64 + lane)*8);
        auA[j] = __builtin_amdgcn_mfma_f32_16x16x32_bf16(aA, bw, auA[j], 0,0,0);
        auB[j] = __builtin_amdgcn_mfma_f32_16x16x32_bf16(aB, bw, auB[j], 0,0,0);
      }
    }
  }
  float invA[4], invB[4];
  #pragma unroll
  for (int r=0;r<4;++r){ invA[r] = 1.f / lrA[r]; invB[r] = 1.f / lrB[r]; }
  #pragma unroll
  for (int j=0;j<4;++j){
    int v = wv*64 + j*16 + qcol;
    float bu = b_U[v];
    #pragma unroll
    for (int r=0;r<4;++r){
      float uA = silu_f(auA[j][r] + bu);
      sUV[(khi + r)*UPAD + v] = f2bf(uA * OA[j][r] * invA[r]);
      float uB = silu_f(auB[j][r] + bu);
      sUV[(16 + khi + r)*UPAD + v] = f2bf(uB * OB[j][r] * invB[r]);
    }
  }
  __syncthreads();

  // ---- out-proj: o = UV @ W_out + b (each wave: 2 n-tiles, both tiles)
  f32x4 aoA[2], aoB[2];
  #pragma unroll
  for (int j=0;j<2;++j){ aoA[j] = (f32x4){0.f,0.f,0.f,0.f}; aoB[j] = (f32x4){0.f,0.f,0.f,0.f}; }
  {
    const short* uvA = &sUV[qcol*UPAD];
    const short* uvB = &sUV[(16 + qcol)*UPAD];
    #pragma unroll
    for (int kt=0; kt<16; ++kt){
      short8v aA = load_afrag(uvA, kt, khi);
      short8v aB = load_afrag(uvB, kt, khi);
      #pragma unroll
      for (int j=0;j<2;++j){
        int nt = wv*2 + j;
        short8v bw = *reinterpret_cast<const short8v*>(Wpo + ((size_t)(nt*16 + kt)*64 + lane)*8);
        aoA[j] = __builtin_amdgcn_mfma_f32_16x16x32_bf16(aA, bw, aoA[j], 0,0,0);
        aoB[j] = __builtin_amdgcn_mfma_f32_16x16x32_bf16(aB, bw, aoB[j], 0,0,0);
      }
    }
  }
  #pragma unroll
  for (int j=0;j<2;++j){
    int col = (wv*2+j)*16 + qcol;
    float bv = b_out[col];
    #pragma unroll
    for (int r=0;r<4;++r){
      aoA[j][r] += bv;  sO[(khi + r)*XPAD + col]      = f2bf(aoA[j][r]);
      aoB[j][r] += bv;  sO[(16 + khi + r)*XPAD + col] = f2bf(aoB[j][r]);
    }
  }
  __syncthreads();

  // ---- gate = sigmoid([o, res] @ W_gate + b); final mix + write, both tiles
  f32x4 agA[2], agB[2];
  #pragma unroll
  for (int j=0;j<2;++j){ agA[j] = (f32x4){0.f,0.f,0.f,0.f}; agB[j] = (f32x4){0.f,0.f,0.f,0.f}; }
  {
    const short* oA = &sO[qcol*XPAD];
    const short* oB = &sO[(16 + qcol)*XPAD];
    const short* rA = &sR[qcol*XPAD];
    const short* rB = &sR[(16 + qcol)*XPAD];
    #pragma unroll
    for (int kt=0; kt<8; ++kt){
      short8v aA = load_afrag(oA, kt, khi);
      short8v aB = load_afrag(oB, kt, khi);
      #pragma unroll
      for (int j=0;j<2;++j){
        int nt = wv*2 + j;
        short8v bw = *reinterpret_cast<const short8v*>(Wpg + ((size_t)(nt*16 + kt)*64 + lane)*8);
        agA[j] = __builtin_amdgcn_mfma_f32_16x16x32_bf16(aA, bw, agA[j], 0,0,0);
        agB[j] = __builtin_amdgcn_mfma_f32_16x16x32_bf16(aB, bw, agB[j], 0,0,0);
      }
    }
    #pragma unroll
    for (int kt=0; kt<8; ++kt){
      short8v aA = load_afrag(rA, kt, khi);
      short8v aB = load_afrag(rB, kt, khi);
      #pragma unroll
      for (int j=0;j<2;++j){
        int nt = wv*2 + j;
        short8v bw = *reinterpret_cast<const short8v*>(Wpg + ((size_t)(nt*16 + 8 + kt)*64 + lane)*8);
        agA[j] = __builtin_amdgcn_mfma_f32_16x16x32_bf16(aA, bw, agA[j], 0,0,0);
        agB[j] = __builtin_amdgcn_mfma_f32_16x16x32_bf16(aB, bw, agB[j], 0,0,0);
      }
    }
  }
  #pragma unroll
  for (int j=0;j<2;++j){
    int col = (wv*2+j)*16 + qcol;
    float bg = b_gate[col];
    #pragma unroll
    for (int r=0;r<4;++r){
      int qA = q0 + khi + r;
      if (qA < S0_){
        float res = seq[((size_t)(b*S_TOT + qA))*D_ + col];
        float g = 1.f/(1.f + __expf(-(agA[j][r] + bg)));
        out[((size_t)(b*S_TOT + qA))*D_ + col] = g*aoA[j][r] + (1.f-g)*res;
      }
      int qB = q0 + 16 + khi + r;
      if (qB < S0_){
        float res = seq[((size_t)(b*S_TOT + qB))*D_ + col];
        float g = 1.f/(1.f + __expf(-(agB[j][r] + bg)));
        out[((size_t)(b*S_TOT + qB))*D_ + col] = g*aoB[j][r] + (1.f-g)*res;
      }
    }
  }
}

extern "C" void kernel_launch(void* const* d_in, const int* in_sizes, int n_in,
                              void* d_out, int out_size, void* d_ws, size_t ws_size,
                              hipStream_t stream)
{
  const float* seq    = (const float*)d_in[0];
  const unsigned char* amask = (const unsigned char*)d_in[1];
  const int*   heights= (const int*)d_in[2];
  const float* W_init = (const float*)d_in[3];
  const float* b_init = (const float*)d_in[4];
  const float* ln_g   = (const float*)d_in[5];
  const float* ln_b   = (const float*)d_in[6];
  const float* W_U    = (const float*)d_in[7];
  const float* b_U    = (const float*)d_in[8];
  const float* W_V    = (const float*)d_in[9];
  const float* b_V    = (const float*)d_in[10];
  const float* W_Z    = (const float*)d_in[11];
  const float* b_Z    = (const float*)d_in[12];
  const float* os_g   = (const float*)d_in[13];
  const float* os_b   = (const float*)d_in[14];
  const float* embH   = (const float*)d_in[15];
  const float* W_out  = (const float*)d_in[16];
  const float* b_out  = (const float*)d_in[17];
  const float* W_gate = (const float*)d_in[18];
  const float* b_gate = (const float*)d_in[19];
  float* out = (float*)d_out;

  char* w = (char*)d_ws;
  short* Zb  = (short*)w;                w += (size_t)16512*128*2;         // bf16 Z row-major
  short* VtF = (short*)w;                w += (size_t)8*32*(2*NT_)*64*8*2; // V B-frags
  short* ZkF = (short*)w;                w += (size_t)NB_*KT16_*4*64*8*2;  // Z-key A-frags
  short* xb  = (short*)w;                w += (size_t)16384*256*2;
  u64*  maskb = (u64*)w;                 w += (size_t)NB_*S0_*NT_*8;
  short* WpI = (short*)w;                w += (size_t)65536*2;
  short* WpU = (short*)w;                w += (size_t)131072*2;
  short* WpV = (short*)w;                w += (size_t)131072*2;
  short* WpZ = (short*)w;                w += (size_t)32768*2;
  short* WpO = (short*)w;                w += (size_t)131072*2;
  short* WpG = (short*)w;                w += (size_t)131072*2;

  hipLaunchKernelGGL(k_prep, dim3(304 + MP_BLOCKS), dim3(256), 0, stream,
      W_init, W_U, W_V, W_Z, W_out, W_gate,
      WpI, WpU, WpV, WpZ, WpO, WpG, amask, maskb);

  hipLaunchKernelGGL(k_x, dim3(256), dim3(256), 0, stream,
      seq, WpI, b_init, ln_g, ln_b, xb, out);

  hipLaunchKernelGGL(k_gemmZV, dim3(512 + 1088), dim3(256), 0, stream,
      xb, WpZ, b_Z, Zb, WpV, b_V, VtF);

  hipLaunchKernelGGL(k_packZ, dim3((NB_*KT16_*4 + 3)/4), dim3(256), 0, stream, Zb, ZkF);

  hipLaunchKernelGGL(k_flash, dim3(256), dim3(512), 0, stream,
      Zb, ZkF, VtF, maskb, xb, WpU, b_U, WpO, b_out, WpG, b_gate,
      seq, out, heights, os_g, os_b, embH);
}

// Round 17
// 95.356 us; speedup vs baseline: 1.1373x; 1.0241x over previous
//
#include <hip/hip_runtime.h>
#include <cstdint>
#include <cstddef>

#define S_TOT 2048
#define S0_   1023
#define S1_   1025
#define D_    256
#define D2_   512
#define DZ_   128
#define NB_   8
#define NT_   17            // 17 * 64 padded keys = 1088
#define KT16_ 68            // 17*4 16-key groups
#define SCALE_INV (1.0f/16.0f)
#define XPAD  264           // 256 + 8 bf16 pad
#define UPAD  520           // 512 + 8 bf16 pad
#define NTILES (NB_*S0_*NT_)        // 139128 mask tiles
#define MP_BLOCKS ((NTILES + 15)/16) // 16 tiles/block (4 per wave)

typedef __attribute__((ext_vector_type(8))) short short8v;
typedef __attribute__((ext_vector_type(4))) short short4v;
typedef __attribute__((ext_vector_type(4))) float f32x4;
typedef unsigned long long u64;

__device__ __forceinline__ short f2bf(float f){
  unsigned u = __float_as_uint(f);
  unsigned r = (u + 0x7FFFu + ((u >> 16) & 1u)) >> 16;
  return (short)r;
}
__device__ __forceinline__ float bf2f(short s){
  return __uint_as_float(((unsigned)(unsigned short)s) << 16);
}
__device__ __forceinline__ float silu_f(float x){ return x / (1.f + __expf(-x)); }

// A/B fragment load from a row-major row (verified layout, round 1):
// elems 0..3: k = kt*32 + khi + j ; elems 4..7: +16
__device__ __forceinline__ short8v load_afrag(const short* arow, int kt, int khi){
  short4v lo = *reinterpret_cast<const short4v*>(arow + kt*32 + khi);
  short4v hi = *reinterpret_cast<const short4v*>(arow + kt*32 + khi + 16);
  short8v r = {lo[0],lo[1],lo[2],lo[3],hi[0],hi[1],hi[2],hi[3]};
  return r;
}

// ------- k_prep: ALL weight packs + mask bitmask pack in ONE launch ---------
__global__ __launch_bounds__(256) void k_prep(
    const float* __restrict__ W_init, const float* __restrict__ W_U,
    const float* __restrict__ W_V,    const float* __restrict__ W_Z,
    const float* __restrict__ W_out,  const float* __restrict__ W_gate,
    short* __restrict__ WpI, short* __restrict__ WpU, short* __restrict__ WpV,
    short* __restrict__ WpZ, short* __restrict__ WpO, short* __restrict__ WpG,
    const unsigned char* __restrict__ amask, u64* __restrict__ maskb)
{
  const int blk = blockIdx.x;
  if (blk < 304){
    const float* W; short* dst; int K, N, base;
    if      (blk <  32){ W=W_init; dst=WpI; K=256; N=256; base=0;   }
    else if (blk <  96){ W=W_U;    dst=WpU; K=256; N=512; base=32;  }
    else if (blk < 160){ W=W_V;    dst=WpV; K=256; N=512; base=96;  }
    else if (blk < 176){ W=W_Z;    dst=WpZ; K=256; N=128; base=160; }
    else if (blk < 240){ W=W_out;  dst=WpO; K=512; N=256; base=176; }
    else               { W=W_gate; dst=WpG; K=512; N=256; base=240; }
    const int wv = threadIdx.x >> 6, lane = threadIdx.x & 63;
    const int KT = K >> 5;
    const int tile = (blk - base)*4 + wv;
    const int nt = tile / KT, kt = tile - nt*KT;
    const int n = nt*16 + (lane & 15);
    const int kbase = kt*32 + ((lane>>4)<<2);
    short8v v;
    #pragma unroll
    for (int j=0;j<8;++j){
      int k = kbase + (j&3) + ((j>>2)<<4);
      v[j] = f2bf(W[(size_t)k*N + n]);
    }
    *reinterpret_cast<short8v*>(dst + ((size_t)tile*64 + lane)*8) = v;
  } else {
    const int lane = threadIdx.x & 63;
    const int g0 = ((blk - 304)*4 + (threadIdx.x >> 6))*4;   // first tile of wave
    #pragma unroll
    for (int j=0;j<4;++j){
      int tg = g0 + j;                 // wave-uniform
      if (tg >= NTILES) break;         // wave-uniform exit
      int row = tg / NT_;              // 0..8183
      int t   = tg - row*NT_;
      int b   = row / S0_;
      int q   = row - b*S0_;
      int key = t*64 + lane;
      unsigned char v = 0;
      if (key < S1_) v = amask[((size_t)(b*S_TOT + q))*S_TOT + S0_ + key];
      u64 bits = __ballot(v != 0);
      if (lane == 0) maskb[tg] = bits;
    }
  }
}

// ---------------- kernel 1a: x = LN(seq@W_init + b) -> bf16; tail rows->out -
__global__ __launch_bounds__(256) void k_x(
    const float* __restrict__ seq, const short* __restrict__ Wp,
    const float* __restrict__ b_init,
    const float* __restrict__ ln_g, const float* __restrict__ ln_b,
    short* __restrict__ xb, float* __restrict__ out)
{
  __shared__ short s_a[64*XPAD];
  const int tid = threadIdx.x, lane = tid & 63, wv = tid >> 6;
  const int R0 = blockIdx.x * 64;
  const int colb = lane & 15, khi = (lane>>4)<<2;

  for (int c = tid; c < 64*64; c += 256){
    int row = c >> 6, c4 = (c & 63) << 2;
    int g = R0 + row;
    float4 f = *reinterpret_cast<const float4*>(seq + (size_t)g*D_ + c4);
    short4v h = { f2bf(f.x), f2bf(f.y), f2bf(f.z), f2bf(f.w) };
    *reinterpret_cast<short4v*>(&s_a[row*XPAD + c4]) = h;
    if ((g & 2047) >= S0_)           // passthrough tail rows
      *reinterpret_cast<float4*>(out + (size_t)g*D_ + c4) = f;
  }
  __syncthreads();

  f32x4 acc[16];
  #pragma unroll
  for (int nt=0;nt<16;++nt) acc[nt] = (f32x4){0.f,0.f,0.f,0.f};

  const short* arow = &s_a[(wv*16 + colb)*XPAD];
  #pragma unroll
  for (int kt=0; kt<8; ++kt){
    short8v a = load_afrag(arow, kt, khi);
    #pragma unroll
    for (int nt=0; nt<16; ++nt){
      short8v b = *reinterpret_cast<const short8v*>(Wp + ((size_t)(nt*8 + kt)*64 + lane)*8);
      acc[nt] = __builtin_amdgcn_mfma_f32_16x16x32_bf16(a, b, acc[nt], 0, 0, 0);
    }
  }

  float sum[4] = {0.f,0.f,0.f,0.f};
  #pragma unroll
  for (int nt=0; nt<16; ++nt){
    float bv = b_init[nt*16 + colb];
    #pragma unroll
    for (int r=0;r<4;++r){ acc[nt][r] += bv; sum[r] += acc[nt][r]; }
  }
  #pragma unroll
  for (int r=0;r<4;++r){
    #pragma unroll
    for (int m=1;m<16;m<<=1) sum[r] += __shfl_xor(sum[r], m, 64);
    sum[r] *= (1.f/256.f);
  }
  float var[4] = {0.f,0.f,0.f,0.f};
  #pragma unroll
  for (int nt=0; nt<16; ++nt)
    #pragma unroll
    for (int r=0;r<4;++r){ float d = acc[nt][r]-sum[r]; var[r] += d*d; }
  #pragma unroll
  for (int r=0;r<4;++r){
    #pragma unroll
    for (int m=1;m<16;m<<=1) var[r] += __shfl_xor(var[r], m, 64);
    var[r] = rsqrtf(var[r]*(1.f/256.f) + 1e-5f);
  }
  #pragma unroll
  for (int nt=0; nt<16; ++nt){
    int col = nt*16 + colb;
    float g = ln_g[col], bb = ln_b[col];
    #pragma unroll
    for (int r=0;r<4;++r){
      float xn = (acc[nt][r]-sum[r])*var[r]*g + bb;
      s_a[(wv*16 + ((lane>>4)<<2) + r)*XPAD + col] = f2bf(xn);
    }
  }
  __syncthreads();
  for (int c = tid; c < 64*32; c += 256){
    int row = c >> 5, c8 = (c & 31) << 3;
    *reinterpret_cast<short8v*>(xb + (size_t)(R0+row)*D_ + c8) =
        *reinterpret_cast<const short8v*>(&s_a[row*XPAD + c8]);
  }
}

// ---- k_gemmZV: Z-gemm (blocks [0,512), emits Zb + ZkF frags) +
//      V-gemm (blocks [512,1600), emits VtF frags) -------------------------
__global__ __launch_bounds__(256) void k_gemmZV(
    const short* __restrict__ xb,
    const short* __restrict__ WpZ, const float* __restrict__ b_Z,
    short* __restrict__ Zb, short* __restrict__ ZkF,
    const short* __restrict__ WpV, const float* __restrict__ b_V,
    short* __restrict__ VtF)
{
  __shared__ short s_a[64*XPAD];
  __shared__ short s_t[64][72];
  const int blk = blockIdx.x;
  const int tid = threadIdx.x, lane = tid & 63, wv = tid >> 6;
  const int wy = wv >> 1, wx = wv & 1;
  const int colb = lane & 15, khi = (lane>>4)<<2;

  if (blk < 512){
    const int R0 = (blk >> 1) * 64;
    const int C0 = (blk & 1) * 64;

    for (int c = tid; c < 64*32; c += 256){
      int r = c >> 5, c8 = (c & 31) << 3;
      size_t xrow = (size_t)(R0 + r);
      *reinterpret_cast<short8v*>(&s_a[r*XPAD + c8]) =
          *reinterpret_cast<const short8v*>(xb + xrow*D_ + c8);
    }
    __syncthreads();

    f32x4 acc[2][2];
    #pragma unroll
    for(int i=0;i<2;++i)
      #pragma unroll
      for(int j=0;j<2;++j) acc[i][j] = (f32x4){0.f,0.f,0.f,0.f};

    const short* ar0 = &s_a[(wy*32 + colb)*XPAD];
    const short* ar1 = ar0 + 16*XPAD;
    const int ntg = (C0 >> 4) + wx*2;
    #pragma unroll
    for (int kt=0; kt<8; ++kt){
      short8v a0 = load_afrag(ar0, kt, khi);
      short8v a1 = load_afrag(ar1, kt, khi);
      short8v b0 = *reinterpret_cast<const short8v*>(WpZ + ((size_t)((ntg+0)*8 + kt)*64 + lane)*8);
      short8v b1 = *reinterpret_cast<const short8v*>(WpZ + ((size_t)((ntg+1)*8 + kt)*64 + lane)*8);
      acc[0][0] = __builtin_amdgcn_mfma_f32_16x16x32_bf16(a0, b0, acc[0][0], 0,0,0);
      acc[0][1] = __builtin_amdgcn_mfma_f32_16x16x32_bf16(a0, b1, acc[0][1], 0,0,0);
      acc[1][0] = __builtin_amdgcn_mfma_f32_16x16x32_bf16(a1, b0, acc[1][0], 0,0,0);
      acc[1][1] = __builtin_amdgcn_mfma_f32_16x16x32_bf16(a1, b1, acc[1][1], 0,0,0);
    }
    // write Zb row-major AND stage values into s_t[row_local][col_local]
    #pragma unroll
    for (int sj=0; sj<2; ++sj){
      int cl = wx*32 + sj*16 + colb;
      int col = C0 + cl;
      float bv = b_Z[col];
      #pragma unroll
      for (int si=0; si<2; ++si){
        #pragma unroll
        for (int r=0;r<4;++r){
          int rl = wy*32 + si*16 + ((lane>>4)<<2) + r;
          short zv = f2bf(silu_f(acc[si][sj][r] + bv));
          Zb[(size_t)(R0 + rl)*DZ_ + col] = zv;
          s_t[rl][cl] = zv;
        }
      }
    }
    __syncthreads();
    // emit ZkF A-fragments for key rows owned by this block
    {
      const int r  = tid >> 2, hi = tid & 3;
      const int g  = R0 + r;
      const int s  = g & 2047;
      const int bb2= g >> 11;
      const int k  = s - S0_;
      if (k >= 0 && k <= 1024){
        const int kt16 = k >> 4, lcol = k & 15;
        const int lane2 = hi*16 + lcol;
        #pragma unroll
        for (int ktl=0; ktl<2; ++ktl){
          const int ktg = (C0 >> 5) + ktl;
          short8v f;
          #pragma unroll
          for (int j=0;j<8;++j){
            int dzl = ktl*32 + hi*4 + (j&3) + ((j>>2)<<4);
            f[j] = s_t[r][dzl];
          }
          size_t o = (((size_t)(bb2*KT16_ + kt16)*4 + ktg)*64 + lane2);
          *reinterpret_cast<short8v*>(ZkF + o*8) = f;
        }
      }
    }
  } else {
    const int idx = blk - 512;
    const int t   = idx % 17;
    const int rest= idx / 17;
    const int C0  = (rest & 7) * 64;
    const int b   = rest >> 3;
    const int R0  = t * 64;

    for (int c = tid; c < 64*32; c += 256){
      int r = c >> 5, c8 = (c & 31) << 3;
      int k = R0 + r; if (k > 1024) k = 1024;
      size_t xrow = (size_t)b*S_TOT + S0_ + k;
      *reinterpret_cast<short8v*>(&s_a[r*XPAD + c8]) =
          *reinterpret_cast<const short8v*>(xb + xrow*D_ + c8);
    }
    __syncthreads();

    f32x4 acc[2][2];
    #pragma unroll
    for(int i=0;i<2;++i)
      #pragma unroll
      for(int j=0;j<2;++j) acc[i][j] = (f32x4){0.f,0.f,0.f,0.f};

    const short* ar0 = &s_a[(wy*32 + colb)*XPAD];
    const short* ar1 = ar0 + 16*XPAD;
    const int ntg = (C0 >> 4) + wx*2;
    #pragma unroll
    for (int kt=0; kt<8; ++kt){
      short8v a0 = load_afrag(ar0, kt, khi);
      short8v a1 = load_afrag(ar1, kt, khi);
      short8v b0 = *reinterpret_cast<const short8v*>(WpV + ((size_t)((ntg+0)*8 + kt)*64 + lane)*8);
      short8v b1 = *reinterpret_cast<const short8v*>(WpV + ((size_t)((ntg+1)*8 + kt)*64 + lane)*8);
      acc[0][0] = __builtin_amdgcn_mfma_f32_16x16x32_bf16(a0, b0, acc[0][0], 0,0,0);
      acc[0][1] = __builtin_amdgcn_mfma_f32_16x16x32_bf16(a0, b1, acc[0][1], 0,0,0);
      acc[1][0] = __builtin_amdgcn_mfma_f32_16x16x32_bf16(a1, b0, acc[1][0], 0,0,0);
      acc[1][1] = __builtin_amdgcn_mfma_f32_16x16x32_bf16(a1, b1, acc[1][1], 0,0,0);
    }
    // silu + transpose into LDS [v_local][key_local]
    #pragma unroll
    for (int sj=0; sj<2; ++sj){
      int cl = wx*32 + sj*16 + colb;
      float bv = b_V[C0 + cl];
      #pragma unroll
      for (int si=0; si<2; ++si){
        #pragma unroll
        for (int r=0;r<4;++r){
          int rl = wy*32 + si*16 + ((lane>>4)<<2) + r;
          s_t[cl][rl] = f2bf(silu_f(acc[si][sj][r] + bv));
        }
      }
    }
    __syncthreads();
    {
      const int vt_l = tid >> 6;
      const int vloc = vt_l*16 + (lane & 15);
      const int krow = (lane>>4)<<2;
      #pragma unroll
      for (int kt=0; kt<2; ++kt){
        short8v f;
        #pragma unroll
        for (int j=0;j<8;++j){
          int kl = kt*32 + krow + (j&3) + ((j>>2)<<4);
          short v = s_t[vloc][kl];
          if (R0 + kl >= S1_) v = 0;
          f[j] = v;
        }
        size_t o = (((size_t)b*32 + (C0>>4) + vt_l)*(2*NT_) + 2*t + kt)*64 + lane;
        *reinterpret_cast<short8v*>(VtF + o*8) = f;
      }
    }
  }
}

// ------ kernel 2: fused flash attention + U-proj + out-proj + gating --------
// block = (batch b, 32-q pair: tiles A and B); 8 waves (512 thr).
#define SMEM_BYTES 103424
__global__ __launch_bounds__(512,2) void k_flash(
    const short* __restrict__ Zb, const short* __restrict__ ZkF,
    const short* __restrict__ VtF, const u64* __restrict__ maskb,
    const short* __restrict__ xb,
    const short* __restrict__ WpU, const float* __restrict__ b_U,
    const short* __restrict__ Wpo, const float* __restrict__ b_out,
    const short* __restrict__ Wpg, const float* __restrict__ b_gate,
    const float* __restrict__ seq, float* __restrict__ out,
    const int* __restrict__ heights,
    const float* __restrict__ os_g, const float* __restrict__ os_b,
    const float* __restrict__ embH)
{
  __shared__ __align__(16) char smem[SMEM_BYTES];
  __shared__ float  s_qh[32][12];
  __shared__ float  s_qb[32];
  __shared__ int    s_hk[NT_*64];
  __shared__ u64    s_mb[32][NT_];
  __shared__ float  s_mxA[8][16], s_mxB[8][16];
  __shared__ float  s_smA[8][16], s_smB[8][16];

  short8v (*s_pAl)[64] = reinterpret_cast<short8v(*)[64]>(smem);           // 17408
  short8v (*s_pAh)[64] = reinterpret_cast<short8v(*)[64]>(smem + 17408);   // ->34816
  short8v (*s_pBl)[64] = reinterpret_cast<short8v(*)[64]>(smem + 34816);   // ->52224
  short8v (*s_pBh)[64] = reinterpret_cast<short8v(*)[64]>(smem + 52224);   // ->69632
  short   (*s_qg)[132] = reinterpret_cast<short(*)[132]>(smem + 34816);    // overlay P_B
  short* sUV = reinterpret_cast<short*>(smem);            // 32*UPAD, overlay P_A
  short* sO  = reinterpret_cast<short*>(smem + 34816);    // 32*XPAD, overlay P_B
  short* sX  = reinterpret_cast<short*>(smem + 69632);    // 32*XPAD
  short* sR  = reinterpret_cast<short*>(smem + 86528);    // 32*XPAD -> 103424

  const int tid = threadIdx.x, lane = tid & 63, wv = tid >> 6;
  const int b  = blockIdx.x & 7;
  const int qp = blockIdx.x >> 3;
  const int q0 = qp * 32;

  // ---- stage x rows (bf16) and res rows (fp32 -> bf16), 32 rows each
  for (int c = tid; c < 32*32; c += 512){
    int r = c >> 5, c8 = (c & 31) << 3;
    int q = min(q0 + r, S0_-1);
    *reinterpret_cast<short8v*>(&sX[r*XPAD + c8]) =
        *reinterpret_cast<const short8v*>(xb + ((size_t)(b*S_TOT + q))*D_ + c8);
  }
  for (int c = tid; c < 32*64; c += 512){
    int r = c >> 6, c4 = (c & 63) << 2;
    int q = min(q0 + r, S0_-1);
    float4 f = *reinterpret_cast<const float4*>(seq + ((size_t)(b*S_TOT + q))*D_ + c4);
    short4v h = { f2bf(f.x), f2bf(f.y), f2bf(f.z), f2bf(f.w) };
    *reinterpret_cast<short4v*>(&sR[r*XPAD + c4]) = h;
  }

  // ---- Q prep: 16 threads per q-row, 8 dz each; 32 rows
  {
    int row = tid >> 4, part = tid & 15;
    int q = q0 + row; if (q > S0_-1) q = S0_-1;
    const short* zrow = Zb + ((size_t)(b*S_TOT + q))*DZ_ + part*8;
    float qb_acc = 0.f;
    float qh_acc[10];
    #pragma unroll
    for (int h=0;h<10;++h) qh_acc[h] = 0.f;
    #pragma unroll
    for (int e=0; e<8; ++e){
      int dz = part*8 + e;
      float z = bf2f(zrow[e]);
      float Q  = z*os_g[dz]      + os_b[dz];
      float Qp = z*os_g[DZ_+dz]  + os_b[DZ_+dz];
      s_qg[row][dz] = f2bf(Q * os_g[2*DZ_+dz]);
      qb_acc += Q * os_b[2*DZ_+dz];
      #pragma unroll
      for (int h=0;h<10;++h) qh_acc[h] += Qp * embH[h*DZ_ + dz];
    }
    #pragma unroll
    for (int m=1;m<16;m<<=1){
      qb_acc += __shfl_xor(qb_acc, m, 64);
      #pragma unroll
      for (int h=0;h<10;++h) qh_acc[h] += __shfl_xor(qh_acc[h], m, 64);
    }
    if (part == 0){
      s_qb[row] = qb_acc;
      #pragma unroll
      for (int h=0;h<10;++h) s_qh[row][h] = qh_acc[h];
    }
  }
  for (int k = tid; k < NT_*64; k += 512)
    s_hk[k] = (k < S1_) ? heights[b*S_TOT + S0_ + k] : 0;
  for (int idx = tid; idx < 32*NT_; idx += 512){
    int qq = idx / NT_, tt = idx - qq*NT_;
    int qr = min(q0 + qq, S0_-1);
    s_mb[qq][tt] = maskb[((size_t)(b*S0_ + qr))*NT_ + tt];
  }
  __syncthreads();

  const int qcol = lane & 15, khi = (lane>>4)<<2;
  const int hqA = heights[b*S_TOT + min(q0 + qcol,      S0_-1)];
  const int hqB = heights[b*S_TOT + min(q0 + 16 + qcol, S0_-1)];
  const float qbA = s_qb[qcol], qbB = s_qb[16 + qcol];

  short8v qgfA[4], qgfB[4];
  #pragma unroll
  for (int kt=0; kt<4; ++kt){
    qgfA[kt] = load_afrag(&s_qg[qcol][0],      kt, khi);
    qgfB[kt] = load_afrag(&s_qg[16 + qcol][0], kt, khi);
  }

  // ---- phase 1: QK for both tiles, shared A-frag loads; per-wave maxima
  f32x4 scA[3][4], scB[3][4];
  float tmA = -1e30f, tmB = -1e30f;
  #pragma unroll
  for (int it=0; it<3; ++it){
    const int t = it*8 + wv;
    if (t < NT_){
      u64 mbA = s_mb[qcol][t], mbB = s_mb[16 + qcol][t];
      #pragma unroll
      for (int st=0; st<4; ++st){
        f32x4 cA = (f32x4){0.f,0.f,0.f,0.f};
        f32x4 cB = (f32x4){0.f,0.f,0.f,0.f};
        #pragma unroll
        for (int kt=0; kt<4; ++kt){
          short8v a = *reinterpret_cast<const short8v*>(
              ZkF + (((size_t)(b*KT16_ + t*4 + st)*4 + kt)*64 + lane)*8);
          cA = __builtin_amdgcn_mfma_f32_16x16x32_bf16(a, qgfA[kt], cA, 0,0,0);
          cB = __builtin_amdgcn_mfma_f32_16x16x32_bf16(a, qgfB[kt], cB, 0,0,0);
        }
        int4 hk4 = *reinterpret_cast<const int4*>(&s_hk[t*64 + st*16 + khi]);
        #pragma unroll
        for (int r=0;r<4;++r){
          int hk = (&hk4.x)[r];
          int kl = st*16 + khi + r;
          int iA = min(max(hk - hqA, 1), 10) - 1;
          float vA = (cA[r] + qbA + s_qh[qcol][iA]) * SCALE_INV;
          vA = ((mbA >> kl) & 1ull) ? vA : -9999.f;
          cA[r] = vA; tmA = fmaxf(tmA, vA);
          int iB = min(max(hk - hqB, 1), 10) - 1;
          float vB = (cB[r] + qbB + s_qh[16 + qcol][iB]) * SCALE_INV;
          vB = ((mbB >> kl) & 1ull) ? vB : -9999.f;
          cB[r] = vB; tmB = fmaxf(tmB, vB);
        }
        scA[it][st] = cA; scB[it][st] = cB;
      }
    }
  }
  tmA = fmaxf(tmA, __shfl_xor(tmA, 16, 64));
  tmA = fmaxf(tmA, __shfl_xor(tmA, 32, 64));
  tmB = fmaxf(tmB, __shfl_xor(tmB, 16, 64));
  tmB = fmaxf(tmB, __shfl_xor(tmB, 32, 64));
  if (lane < 16){ s_mxA[wv][lane] = tmA; s_mxB[wv][lane] = tmB; }
  __syncthreads();

  // ---- phase 2: exact global max, exp, pack P for both tiles
  float mA = -1e30f, mB = -1e30f;
  #pragma unroll
  for (int w=0; w<8; ++w){
    mA = fmaxf(mA, s_mxA[w][qcol]);
    mB = fmaxf(mB, s_mxB[w][qcol]);
  }
  float lsA = 0.f, lsB = 0.f;
  #pragma unroll
  for (int it=0; it<3; ++it){
    const int t = it*8 + wv;
    if (t < NT_){
      #pragma unroll
      for (int st=0; st<4; ++st)
        #pragma unroll
        for (int r=0;r<4;++r){
          float pA = __expf(scA[it][st][r] - mA); lsA += pA; scA[it][st][r] = pA;
          float pB = __expf(scB[it][st][r] - mB); lsB += pB; scB[it][st][r] = pB;
        }
      short8v a0, a1, b0, b1;
      #pragma unroll
      for (int j=0;j<8;++j){
        a0[j] = f2bf(scA[it][(j>>2)][j&3]);
        a1[j] = f2bf(scA[it][2 + (j>>2)][j&3]);
        b0[j] = f2bf(scB[it][(j>>2)][j&3]);
        b1[j] = f2bf(scB[it][2 + (j>>2)][j&3]);
      }
      s_pAl[t][lane] = a0; s_pAh[t][lane] = a1;
      s_pBl[t][lane] = b0; s_pBh[t][lane] = b1;
    }
  }
  lsA += __shfl_xor(lsA, 16, 64); lsA += __shfl_xor(lsA, 32, 64);
  lsB += __shfl_xor(lsB, 16, 64); lsB += __shfl_xor(lsB, 32, 64);
  if (lane < 16){ s_smA[wv][lane] = lsA; s_smB[wv][lane] = lsB; }
  __syncthreads();

  // ---- phase 3: PV, each wave owns 64 v-cols, both tiles off shared V loads
  float lrA[4], lrB[4];
  #pragma unroll
  for (int r=0;r<4;++r){
    int qr = khi + r;
    float sa = 0.f, sb = 0.f;
    #pragma unroll
    for (int w=0; w<8; ++w){ sa += s_smA[w][qr]; sb += s_smB[w][qr]; }
    lrA[r] = sa; lrB[r] = sb;
  }
  f32x4 OA[4], OB[4];
  #pragma unroll
  for (int j=0;j<4;++j){ OA[j] = (f32x4){0.f,0.f,0.f,0.f}; OB[j] = (f32x4){0.f,0.f,0.f,0.f}; }
  for (int t=0; t<NT_; ++t){
    short8v pa0 = s_pAl[t][lane], pa1 = s_pAh[t][lane];
    short8v pb0 = s_pBl[t][lane], pb1 = s_pBh[t][lane];
    #pragma unroll
    for (int j=0;j<4;++j){
      size_t vb = ((size_t)b*32 + wv*4 + j)*(2*NT_) + 2*t;
      short8v v0 = *reinterpret_cast<const short8v*>(VtF + (vb*64 + lane)*8);
      short8v v1 = *reinterpret_cast<const short8v*>(VtF + ((vb+1)*64 + lane)*8);
      OA[j] = __builtin_amdgcn_mfma_f32_16x16x32_bf16(pa0, v0, OA[j], 0,0,0);
      OA[j] = __builtin_amdgcn_mfma_f32_16x16x32_bf16(pa1, v1, OA[j], 0,0,0);
      OB[j] = __builtin_amdgcn_mfma_f32_16x16x32_bf16(pb0, v0, OB[j], 0,0,0);
      OB[j] = __builtin_amdgcn_mfma_f32_16x16x32_bf16(pb1, v1, OB[j], 0,0,0);
    }
  }
  __syncthreads();   // P buffers die; sUV/sO region born

  // ---- U = silu(x @ W_U + b) for own 64 v-cols; uv = U*O/l -> sUV (both tiles)
  f32x4 auA[4], auB[4];
  #pragma unroll
  for (int j=0;j<4;++j){ auA[j] = (f32x4){0.f,0.f,0.f,0.f}; auB[j] = (f32x4){0.f,0.f,0.f,0.f}; }
  {
    const short* xrA = &sX[qcol*XPAD];
    const short* xrB = &sX[(16 + qcol)*XPAD];
    #pragma unroll
    for (int kt=0; kt<8; ++kt){
      short8v aA = load_afrag(xrA, kt, khi);
      short8v aB = load_afrag(xrB, kt, khi);
      #pragma unroll
      for (int j=0;j<4;++j){
        int nt = wv*4 + j;
        short8v bw = *reinterpret_cast<const short8v*>(WpU + ((size_t)(nt*8 + kt)*64 + lane)*8);
        auA[j] = __builtin_amdgcn_mfma_f32_16x16x32_bf16(aA, bw, auA[j], 0,0,0);
        auB[j] = __builtin_amdgcn_mfma_f32_16x16x32_bf16(aB, bw, auB[j], 0,0,0);
      }
    }
  }
  float invA[4], invB[4];
  #pragma unroll
  for (int r=0;r<4;++r){ invA[r] = 1.f / lrA[r]; invB[r] = 1.f / lrB[r]; }
  #pragma unroll
  for (int j=0;j<4;++j){
    int v = wv*64 + j*16 + qcol;
    float bu = b_U[v];
    #pragma unroll
    for (int r=0;r<4;++r){
      float uA = silu_f(auA[j][r] + bu);
      sUV[(khi + r)*UPAD + v] = f2bf(uA * OA[j][r] * invA[r]);
      float uB = silu_f(auB[j][r] + bu);
      sUV[(16 + khi + r)*UPAD + v] = f2bf(uB * OB[j][r] * invB[r]);
    }
  }
  __syncthreads();

  // ---- out-proj: o = UV @ W_out + b (each wave: 2 n-tiles, both tiles)
  f32x4 aoA[2], aoB[2];
  #pragma unroll
  for (int j=0;j<2;++j){ aoA[j] = (f32x4){0.f,0.f,0.f,0.f}; aoB[j] = (f32x4){0.f,0.f,0.f,0.f}; }
  {
    const short* uvA = &sUV[qcol*UPAD];
    const short* uvB = &sUV[(16 + qcol)*UPAD];
    #pragma unroll
    for (int kt=0; kt<16; ++kt){
      short8v aA = load_afrag(uvA, kt, khi);
      short8v aB = load_afrag(uvB, kt, khi);
      #pragma unroll
      for (int j=0;j<2;++j){
        int nt = wv*2 + j;
        short8v bw = *reinterpret_cast<const short8v*>(Wpo + ((size_t)(nt*16 + kt)*64 + lane)*8);
        aoA[j] = __builtin_amdgcn_mfma_f32_16x16x32_bf16(aA, bw, aoA[j], 0,0,0);
        aoB[j] = __builtin_amdgcn_mfma_f32_16x16x32_bf16(aB, bw, aoB[j], 0,0,0);
      }
    }
  }
  #pragma unroll
  for (int j=0;j<2;++j){
    int col = (wv*2+j)*16 + qcol;
    float bv = b_out[col];
    #pragma unroll
    for (int r=0;r<4;++r){
      aoA[j][r] += bv;  sO[(khi + r)*XPAD + col]      = f2bf(aoA[j][r]);
      aoB[j][r] += bv;  sO[(16 + khi + r)*XPAD + col] = f2bf(aoB[j][r]);
    }
  }
  __syncthreads();

  // ---- gate = sigmoid([o, res] @ W_gate + b); final mix + write, both tiles
  f32x4 agA[2], agB[2];
  #pragma unroll
  for (int j=0;j<2;++j){ agA[j] = (f32x4){0.f,0.f,0.f,0.f}; agB[j] = (f32x4){0.f,0.f,0.f,0.f}; }
  {
    const short* oA = &sO[qcol*XPAD];
    const short* oB = &sO[(16 + qcol)*XPAD];
    const short* rA = &sR[qcol*XPAD];
    const short* rB = &sR[(16 + qcol)*XPAD];
    #pragma unroll
    for (int kt=0; kt<8; ++kt){
      short8v aA = load_afrag(oA, kt, khi);
      short8v aB = load_afrag(oB, kt, khi);
      #pragma unroll
      for (int j=0;j<2;++j){
        int nt = wv*2 + j;
        short8v bw = *reinterpret_cast<const short8v*>(Wpg + ((size_t)(nt*16 + kt)*64 + lane)*8);
        agA[j] = __builtin_amdgcn_mfma_f32_16x16x32_bf16(aA, bw, agA[j], 0,0,0);
        agB[j] = __builtin_amdgcn_mfma_f32_16x16x32_bf16(aB, bw, agB[j], 0,0,0);
      }
    }
    #pragma unroll
    for (int kt=0; kt<8; ++kt){
      short8v aA = load_afrag(rA, kt, khi);
      short8v aB = load_afrag(rB, kt, khi);
      #pragma unroll
      for (int j=0;j<2;++j){
        int nt = wv*2 + j;
        short8v bw = *reinterpret_cast<const short8v*>(Wpg + ((size_t)(nt*16 + 8 + kt)*64 + lane)*8);
        agA[j] = __builtin_amdgcn_mfma_f32_16x16x32_bf16(aA, bw, agA[j], 0,0,0);
        agB[j] = __builtin_amdgcn_mfma_f32_16x16x32_bf16(aB, bw, agB[j], 0,0,0);
      }
    }
  }
  #pragma unroll
  for (int j=0;j<2;++j){
    int col = (wv*2+j)*16 + qcol;
    float bg = b_gate[col];
    #pragma unroll
    for (int r=0;r<4;++r){
      int qA = q0 + khi + r;
      if (qA < S0_){
        float res = seq[((size_t)(b*S_TOT + qA))*D_ + col];
        float g = 1.f/(1.f + __expf(-(agA[j][r] + bg)));
        out[((size_t)(b*S_TOT + qA))*D_ + col] = g*aoA[j][r] + (1.f-g)*res;
      }
      int qB = q0 + 16 + khi + r;
      if (qB < S0_){
        float res = seq[((size_t)(b*S_TOT + qB))*D_ + col];
        float g = 1.f/(1.f + __expf(-(agB[j][r] + bg)));
        out[((size_t)(b*S_TOT + qB))*D_ + col] = g*aoB[j][r] + (1.f-g)*res;
      }
    }
  }
}

extern "C" void kernel_launch(void* const* d_in, const int* in_sizes, int n_in,
                              void* d_out, int out_size, void* d_ws, size_t ws_size,
                              hipStream_t stream)
{
  const float* seq    = (const float*)d_in[0];
  const unsigned char* amask = (const unsigned char*)d_in[1];
  const int*   heights= (const int*)d_in[2];
  const float* W_init = (const float*)d_in[3];
  const float* b_init = (const float*)d_in[4];
  const float* ln_g   = (const float*)d_in[5];
  const float* ln_b   = (const float*)d_in[6];
  const float* W_U    = (const float*)d_in[7];
  const float* b_U    = (const float*)d_in[8];
  const float* W_V    = (const float*)d_in[9];
  const float* b_V    = (const float*)d_in[10];
  const float* W_Z    = (const float*)d_in[11];
  const float* b_Z    = (const float*)d_in[12];
  const float* os_g   = (const float*)d_in[13];
  const float* os_b   = (const float*)d_in[14];
  const float* embH   = (const float*)d_in[15];
  const float* W_out  = (const float*)d_in[16];
  const float* b_out  = (const float*)d_in[17];
  const float* W_gate = (const float*)d_in[18];
  const float* b_gate = (const float*)d_in[19];
  float* out = (float*)d_out;

  char* w = (char*)d_ws;
  short* Zb  = (short*)w;                w += (size_t)16512*128*2;         // bf16 Z row-major
  short* VtF = (short*)w;                w += (size_t)8*32*(2*NT_)*64*8*2; // V B-frags
  short* ZkF = (short*)w;                w += (size_t)NB_*KT16_*4*64*8*2;  // Z-key A-frags
  short* xb  = (short*)w;                w += (size_t)16384*256*2;
  u64*  maskb = (u64*)w;                 w += (size_t)NB_*S0_*NT_*8;
  short* WpI = (short*)w;                w += (size_t)65536*2;
  short* WpU = (short*)w;                w += (size_t)131072*2;
  short* WpV = (short*)w;                w += (size_t)131072*2;
  short* WpZ = (short*)w;                w += (size_t)32768*2;
  short* WpO = (short*)w;                w += (size_t)131072*2;
  short* WpG = (short*)w;                w += (size_t)131072*2;

  hipLaunchKernelGGL(k_prep, dim3(304 + MP_BLOCKS), dim3(256), 0, stream,
      W_init, W_U, W_V, W_Z, W_out, W_gate,
      WpI, WpU, WpV, WpZ, WpO, WpG, amask, maskb);

  hipLaunchKernelGGL(k_x, dim3(256), dim3(256), 0, stream,
      seq, WpI, b_init, ln_g, ln_b, xb, out);

  hipLaunchKernelGGL(k_gemmZV, dim3(512 + 1088), dim3(256), 0, stream,
      xb, WpZ, b_Z, Zb, ZkF, WpV, b_V, VtF);

  hipLaunchKernelGGL(k_flash, dim3(256), dim3(512), 0, stream,
      Zb, ZkF, VtF, maskb, xb, WpU, b_U, WpO, b_out, WpG, b_gate,
      seq, out, heights, os_g, os_b, embH);
}